// Round 10
// baseline (598.881 us; speedup 1.0000x reference)
//
#include <hip/hip_runtime.h>

// Convattn: B=16, N=740 (256+484), C=768, H=12, hd=64. Inputs/outputs fp32.
// R10 structure: prep (WT transpose + bias) -> gemm_qkv (A-panel-resident)
// -> attn (T14 issue-early) -> proj.
// gemm_qkv: 370 blocks x 512 thr. Block = one 64-row A-panel staged ONCE into
// 96KB LDS (fp32->bf16 inline, XOR-swizzled rows); loops over output panels
// (Q-type: 6, KV-type: 12) x 12 K-steps staging only B (16KB, 2-phase dbuf).
// ws layout CTX | V | Q | K | BIAS2 | WT. WT planes [q][k][v][p], q-plane
// pre-scaled 0.125*log2e; BIAS2 repacked [h][row][jb][ln][nt] pre-scaled
// log2e. Softmax = exp2(s+b), MFMA C-init -SMAX*log2e.

typedef unsigned short u16;
typedef short bf16x8 __attribute__((ext_vector_type(8)));
typedef float f32x4 __attribute__((ext_vector_type(4)));

#define BSZ   16
#define NTOK  740
#define NTMP  256
#define NTGT  484
#define DIMC  768
#define NHEAD 12
#define HDIM  64
#define MROWS (BSZ*NTOK)      // 11840
#define LOG2E 1.44269504f
#define NEGS  (-23.0831032f)  // -16 * log2e (fixed softmax max, scores ~|6|)

__device__ __forceinline__ float bflo(unsigned int u) {
    return __uint_as_float(u << 16);
}
__device__ __forceinline__ float bfhi(unsigned int u) {
    return __uint_as_float(u & 0xffff0000u);
}
__device__ __forceinline__ u16 f2bf(float f) {
    unsigned int u = __float_as_uint(f);
    u += 0x7fffu + ((u >> 16) & 1u);   // RNE
    return (u16)(u >> 16);
}

// async 16B global -> LDS (gfx950). LDS dest must be wave base + lane*16.
__device__ __forceinline__ void gl_lds16(const u16* g, u16* l) {
    __builtin_amdgcn_global_load_lds(
        (const __attribute__((address_space(1))) unsigned int*)(unsigned long long)g,
        (__attribute__((address_space(3))) unsigned int*)(unsigned int)(unsigned long long)l,
        16, 0, 0);
}

// repacked bias offset: [h][i][jb][ln][nt]
__device__ __forceinline__ size_t b2off(int h, int i, int j) {
    return ((size_t)(h * NTOK + i)) * 768 + ((j >> 6) << 6) + ((j & 15) << 2) + ((j >> 4) & 3);
}

// ---------------------------------------------------------------------------
// prep: MLP (first, long serial blocks overlap) + weight transpose + bias
// diagonal. grid = 484 + 576 + 2220 = 3280. (R9 body, unchanged.)
// ---------------------------------------------------------------------------
#define PREP_MLP  484
#define PREP_TRW  (PREP_MLP + 576)     // 1060
#define PREP_ALL  (PREP_TRW + 2220)    // 3280

__global__ __launch_bounds__(256) void prep_kernel(
    const float* __restrict__ w0, const float* __restrict__ w1,
    const float* __restrict__ w2, const float* __restrict__ w3,
    u16* __restrict__ Wt,
    const float* __restrict__ rpb, const float* __restrict__ rpbt,
    const int* __restrict__ tidx, const int* __restrict__ gidx,
    const float* __restrict__ pw1, const float* __restrict__ pb1,
    const float* __restrict__ pw2, const float* __restrict__ pb2,
    const float* __restrict__ tab, u16* __restrict__ bias)
{
    __shared__ float T[64][65];
    const int blk = blockIdx.x;
    const int tid = threadIdx.x;

    if (blk < PREP_MLP) {
        int g = blk;                      // 0..483
        int t = tid;                      // 0..255
        float a  = tab[(g * NTMP + t) * 2 + 0];
        float bb = tab[(g * NTMP + t) * 2 + 1];
        float acc[NHEAD];
        #pragma unroll
        for (int h = 0; h < NHEAD; h++) acc[h] = pb2[h];
        for (int k = 0; k < 512; k++) {
            float hid = fmaxf(a * pw1[k] + bb * pw1[512 + k] + pb1[k], 0.0f);
            #pragma unroll
            for (int h = 0; h < NHEAD; h++) acc[h] += hid * pw2[k * NHEAD + h];
        }
        #pragma unroll
        for (int h = 0; h < NHEAD; h++) {
            u16 v = f2bf(acc[h] * LOG2E);
            bias[b2off(h, t, NTMP + g)] = v;   // top-right
            bias[b2off(h, NTMP + g, t)] = v;   // bottom-left
        }
    } else if (blk < PREP_TRW) {
        int t = blk - PREP_MLP;           // 0..575
        int z = t / 144, rem = t - z * 144;
        int bx = rem % 12, by = rem / 12;
        const float* src = (z == 0) ? w0 : (z == 1) ? w1 : (z == 2) ? w2 : w3;
        const float scale = (z == 0) ? 0.125f * LOG2E : 1.0f;
        u16* dst = Wt + (size_t)z * DIMC * DIMC;
        int out0 = bx * 64, in0 = by * 64;
        #pragma unroll
        for (int l = 0; l < 4; l++) {
            int u = tid + (l << 8);
            int r = u >> 4, c4 = (u & 15) << 2;
            float4 p = *(const float4*)(src + (size_t)(in0 + r) * DIMC + out0 + c4);
            T[r][c4] = p.x; T[r][c4 + 1] = p.y; T[r][c4 + 2] = p.z; T[r][c4 + 3] = p.w;
        }
        __syncthreads();
        #pragma unroll
        for (int l = 0; l < 2; l++) {
            int u = tid + (l << 8);
            int r = u >> 3, c8 = (u & 7) << 3;
            u16 e[8];
            #pragma unroll
            for (int i = 0; i < 8; i++) e[i] = f2bf(T[c8 + i][r] * scale);
            *(uint4*)(dst + (size_t)(out0 + r) * DIMC + in0 + c8) = *(uint4*)e;
        }
    } else {
        int t = blk - PREP_TRW;           // 0..2219
        int jb = t % 3, i = t / 3;
        int j = jb * 256 + tid;
        u16 vals[NHEAD];
        if (j >= NTOK) {
            u16 neg = f2bf(-1e30f);
            #pragma unroll
            for (int h = 0; h < NHEAD; h++) vals[h] = neg;
        } else if (i < NTMP && j < NTMP) {
            int idx = tidx[i * NTMP + j];
            #pragma unroll
            for (int h = 0; h < NHEAD; h++) vals[h] = f2bf(rpbt[idx * NHEAD + h] * LOG2E);
        } else if (i >= NTMP && j >= NTMP) {
            int idx = gidx[(i - NTMP) * NTGT + (j - NTMP)];
            #pragma unroll
            for (int h = 0; h < NHEAD; h++) vals[h] = f2bf(rpb[idx * NHEAD + h] * LOG2E);
        } else {
            return;  // cross region
        }
        #pragma unroll
        for (int h = 0; h < NHEAD; h++) bias[b2off(h, i, j)] = vals[h];
    }
}

// ---------------------------------------------------------------------------
// A-panel-resident QKV GEMM. 370 blocks x 512 thr (8 waves).
// Block by<185 = Q-type (A = tq/gq, 6 output panels, plane q); by>=185 =
// KV-type (A = x, 12 panels: 6 K then 6 V). A: 64 rows x 768 k staged ONCE
// (fp32 load, f2bf, ds_write_b128 at XOR-swizzled row rr^qe, chunk j*8+qe —
// conflict-free, key matches read side (kp*4+quad)). B: 128x64 tile per
// K-step via gl_lds16, 2-phase double-buffer (T3-minimum), ONE barrier per
// step. Per wave per panel: out 32x32 (acc[2][2]); wm=(w>>2)*32, wn=(w&3)*32.
// LDS = 96KB A + 32KB B = 128KB -> 1 block/CU; per-step staging (16KB L2-hot
// B) < compute (8 waves x 8 MFMA) -> compute-bound loop.
// ---------------------------------------------------------------------------
__global__ __launch_bounds__(512) void gemm_qkv(
    const float* __restrict__ x, const float* __restrict__ tq,
    const float* __restrict__ gq, const u16* __restrict__ Wt,
    u16* __restrict__ Qo, u16* __restrict__ Ko, u16* __restrict__ Vo)
{
    __shared__ __align__(16) u16 As[96 * 64 * 8];   // [chunk(96)][row^key(64)][8] 96KB
    __shared__ __align__(16) u16 Bs[2][8192];       // [buf][chunk(8)][row(128)][8] 32KB
    const int tid = threadIdx.x;                    // 0..511
    const int lane = tid & 63, w = tid >> 6;        // 8 waves
    const int quad = lane >> 4, ln = lane & 15;

    // bijective XCD-chunked swizzle over 370 blocks
    const int nwg = 370;
    const int flat = blockIdx.x;
    const int q = nwg >> 3, r = nwg & 7;            // 46, 2
    const int xcd = flat & 7, sidx = flat >> 3;
    const int wg = (xcd < r) ? xcd * (q + 1) + sidx
                             : r * (q + 1) + (xcd - r) * q + sidx;
    const int kvtype = (wg >= 185) ? 1 : 0;
    const int by = kvtype ? (wg - 185) : wg;
    const int m0 = by << 6;

    const int wm = (w >> 2) << 5;                   // 0 / 32
    const int wn = (w & 3) << 5;                    // 0,32,64,96

    // ---- stage A panel once: 64 rows x 768 k, fp32 -> bf16, swizzled ----
    const int rr = tid >> 3, qe = tid & 7;
    const int arow = m0 + rr;
    const float* aptr;
    if (!kvtype) {
        int b = arow / NTOK, n = arow - b * NTOK;
        aptr = (n < NTMP) ? tq + ((size_t)(b * NTMP + n)) * DIMC
                          : gq + ((size_t)(b * NTGT + (n - NTMP))) * DIMC;
    } else {
        aptr = x + (size_t)arow * DIMC;
    }
    #pragma unroll
    for (int j = 0; j < 12; j++) {
        const float* s = aptr + j * 64 + qe * 8;
        float4 a0 = ((const float4*)s)[0], a1 = ((const float4*)s)[1];
        u16 e[8] = {f2bf(a0.x), f2bf(a0.y), f2bf(a0.z), f2bf(a0.w),
                    f2bf(a1.x), f2bf(a1.y), f2bf(a1.z), f2bf(a1.w)};
        *(uint4*)&As[((j * 8 + qe) * 64 + (rr ^ qe)) * 8] = *(uint4*)e;
    }

#define WB_OF(pi) ((!kvtype) ? (Wt + ((size_t)(pi) << 7) * DIMC)                          \
                 : ((pi) < 6) ? (Wt + (size_t)DIMC * DIMC + ((size_t)(pi) << 7) * DIMC)   \
                              : (Wt + 2 * (size_t)DIMC * DIMC + ((size_t)((pi) - 6) << 7) * DIMC))

#define STAGEB(Wb, t, s) do {                                                 \
    _Pragma("unroll")                                                         \
    for (int l = 0; l < 2; l++) {                                             \
        int f = tid + (l << 9);                                               \
        int c8 = f >> 7, r2 = f & 127;                                        \
        gl_lds16((Wb) + (size_t)r2 * DIMC + ((t) << 6) + c8 * 8,              \
                 &Bs[s][f * 8]);                                              \
    } } while (0)

    const int NP = kvtype ? 12 : 6;
    STAGEB(WB_OF(0), 0, 0);
    __syncthreads();                 // A ds_writes + B[0] visible

    int buf = 0;
    for (int pi = 0; pi < NP; pi++) {
        const u16* WbC = WB_OF(pi);
        const u16* WbN = (pi + 1 < NP) ? WB_OF(pi + 1) : WbC;
        f32x4 acc[2][2];
        #pragma unroll
        for (int i = 0; i < 2; i++)
            #pragma unroll
            for (int j = 0; j < 2; j++) acc[i][j] = (f32x4){0.f, 0.f, 0.f, 0.f};

        #pragma unroll 1
        for (int t = 0; t < 12; t++) {
            if (!((pi == NP - 1) && (t == 11))) {
                const u16* Ws = (t < 11) ? WbC : WbN;
                int tn = (t < 11) ? (t + 1) : 0;
                STAGEB(Ws, tn, buf ^ 1);
            }
            #pragma unroll
            for (int kp = 0; kp < 2; kp++) {
                const int key = (kp << 2) + quad;        // == chunk & 7
                const int C = (t << 3) + key;
                bf16x8 af[2], bfr[2];
                #pragma unroll
                for (int mt = 0; mt < 2; mt++)
                    af[mt] = *(const bf16x8*)
                        &As[(C * 64 + ((wm + mt * 16 + ln) ^ key)) * 8];
                #pragma unroll
                for (int nt = 0; nt < 2; nt++)
                    bfr[nt] = *(const bf16x8*)
                        &Bs[buf][(key * 128 + wn + nt * 16 + ln) * 8];
                #pragma unroll
                for (int mt = 0; mt < 2; mt++)
                    #pragma unroll
                    for (int nt = 0; nt < 2; nt++)
                        acc[mt][nt] = __builtin_amdgcn_mfma_f32_16x16x32_bf16(
                            af[mt], bfr[nt], acc[mt][nt], 0, 0, 0);
            }
            __syncthreads();         // readers done + next B drained
            buf ^= 1;
        }

        // write panel pi
        u16* Co; int nn;
        if (!kvtype)      { Co = Qo; nn = pi << 7; }
        else if (pi < 6)  { Co = Ko; nn = pi << 7; }
        else              { Co = Vo; nn = (pi - 6) << 7; }
        #pragma unroll
        for (int mt = 0; mt < 2; mt++)
            #pragma unroll
            for (int reg = 0; reg < 4; reg++) {
                int grow = m0 + wm + mt * 16 + (quad << 2) + reg;
                #pragma unroll
                for (int nt = 0; nt < 2; nt++)
                    Co[(size_t)grow * DIMC + nn + wn + nt * 16 + ln]
                        = f2bf(acc[mt][nt][reg]);
            }
    }
#undef WB_OF
#undef STAGEB
}

// ---------------------------------------------------------------------------
// proj GEMM: BM=64, BN=128, A = CTX bf16 via gl_lds, fp32 out + bias.
// grid (6, 185), single-buffered, XCD swizzle. (R9 body, unchanged.)
// ---------------------------------------------------------------------------
__global__ __launch_bounds__(256) void gemm_proj(
    const u16* __restrict__ A, const u16* __restrict__ Wt,
    const float* __restrict__ pb, float* __restrict__ Cf)
{
    __shared__ __align__(16) u16 As[4096];   // 8KB
    __shared__ __align__(16) u16 Bs[8192];   // 16KB
    const int tid = threadIdx.x;
    const int lane = tid & 63, w = tid >> 6;
    const int quad = lane >> 4, ln = lane & 15;

    const int nwg = 6 * 185;
    const int flat = blockIdx.y * 6 + blockIdx.x;
    const int q = nwg >> 3, r = nwg & 7;
    const int xcd = flat & 7, sidx = flat >> 3;
    const int wg = (xcd < r) ? xcd * (q + 1) + sidx
                             : r * (q + 1) + (xcd - r) * q + sidx;
    const int by = wg / 6, bx = wg - by * 6;

    const int m0 = by << 6;
    const int wm = (w >> 1) << 5, wn = (w & 1) << 6;
    const int nn = bx << 7;
    const u16* Wb = Wt + (size_t)nn * DIMC;

    f32x4 acc[2][4];
    #pragma unroll
    for (int i = 0; i < 2; i++)
        #pragma unroll
        for (int j = 0; j < 4; j++) acc[i][j] = (f32x4){0.f, 0.f, 0.f, 0.f};

    #pragma unroll 1
    for (int t = 0; t < 12; t++) {
        __syncthreads();
        const int k0 = t << 6;
        #pragma unroll
        for (int l = 0; l < 2; l++) {
            int f = tid + (l << 8);
            int c8 = f >> 6, r2 = f & 63;
            gl_lds16(A + (size_t)(m0 + r2) * DIMC + k0 + c8 * 8, &As[f * 8]);
        }
        #pragma unroll
        for (int l = 0; l < 4; l++) {
            int f = tid + (l << 8);
            int c8 = f >> 7, r2 = f & 127;
            gl_lds16(Wb + (size_t)r2 * DIMC + k0 + c8 * 8, &Bs[f * 8]);
        }
        __syncthreads();
        #pragma unroll
        for (int kp = 0; kp < 2; kp++) {
            bf16x8 af[2], bfr[4];
            #pragma unroll
            for (int mt = 0; mt < 2; mt++)
                af[mt] = *(const bf16x8*)
                    &As[(((kp << 2) + quad) * 64 + wm + mt * 16 + ln) * 8];
            #pragma unroll
            for (int nt = 0; nt < 4; nt++)
                bfr[nt] = *(const bf16x8*)
                    &Bs[(((kp << 2) + quad) * 128 + wn + nt * 16 + ln) * 8];
            #pragma unroll
            for (int mt = 0; mt < 2; mt++)
                #pragma unroll
                for (int nt = 0; nt < 4; nt++)
                    acc[mt][nt] = __builtin_amdgcn_mfma_f32_16x16x32_bf16(
                        af[mt], bfr[nt], acc[mt][nt], 0, 0, 0);
        }
    }

    #pragma unroll
    for (int mt = 0; mt < 2; mt++)
        #pragma unroll
        for (int reg = 0; reg < 4; reg++) {
            int grow = m0 + wm + mt * 16 + (quad << 2) + reg;
            #pragma unroll
            for (int nt = 0; nt < 4; nt++) {
                int gcol = nn + wn + nt * 16 + ln;
                Cf[(size_t)grow * DIMC + gcol] = acc[mt][nt][reg] + pb[gcol];
            }
        }
}

// ---------------------------------------------------------------------------
// Flash MFMA attention, T14 issue-early/write-late. 64 Q-rows/block, 4 waves;
// grid 2304, h-major XCD remap (8*288). K double-buffered (gl_lds) so tile
// t+1's K/V/bias loads are issued BEFORE tile t's compute — the end-of-compute
// barrier drains already-landed loads instead of exposing full latency.
// LDS 16K (K dbuf) + 9K (Vt) + 9K (Pw) = 34.8KB -> 4 blocks/CU preserved.
// exp2 softmax, C-init -SMAX*log2e.
// ---------------------------------------------------------------------------
__global__ __launch_bounds__(256) void attn_mfma(
    const u16* __restrict__ Qg, const u16* __restrict__ Kg,
    const u16* __restrict__ Vg, const u16* __restrict__ bias,
    u16* __restrict__ ctx)
{
    __shared__ __align__(16) u16 KsL[2][4096];     // [buf][chunk(8)][jr(64)][8]
    __shared__ __align__(16) u16 VtL[64 * 72];     // [d][j^swz], stride 72
    __shared__ __align__(16) u16 Pw[4][16][72];    // [w][m][k^swz]

    const int tid = threadIdx.x;
    const int lane = tid & 63, w = tid >> 6;
    const int quad = lane >> 4, ln = lane & 15;

    // h-major XCD-chunked remap (bijective: 2304 = 8 * 288).
    const int flat = (blockIdx.z * 12 + blockIdx.y) * 12 + blockIdx.x;
    const int wg = (flat & 7) * 288 + (flat >> 3);
    const int h = wg / 192;
    const int rem = wg - h * 192;
    const int b = rem / 12;
    const int q0 = (rem - b * 12) << 6;

    const int mbase = q0 + (w << 4);               // wave's 16 rows
    const u16* bp = bias + ((size_t)h * NTOK) * 768;

    // Q fragments (A-layout), held for the whole kernel
    bf16x8 aq[2];
    {
        int qrow = mbase + ln; if (qrow >= NTOK) qrow = NTOK - 1;
        #pragma unroll
        for (int kp = 0; kp < 2; kp++)
            aq[kp] = *(const bf16x8*)(Qg + ((size_t)(b * NTOK + qrow)) * DIMC
                                      + h * HDIM + kp * 32 + (quad << 3));
    }
    int boff[4];
    #pragma unroll
    for (int reg = 0; reg < 4; reg++) {
        int rr = mbase + (quad << 2) + reg;
        if (rr >= NTOK) rr = NTOK - 1;
        boff[reg] = rr * 768 + (ln << 2);
    }

    // V staging geometry (per thread, fixed)
    int vjr[2], vd0[2];
    #pragma unroll
    for (int l = 0; l < 2; l++) {
        int u = tid + (l << 8);
        vjr[l] = u >> 3; vd0[l] = (u & 7) << 3;
    }

    // P read swizzle constant (row = ln)
    const int pswz = ((ln >> 2) & 3) << 4;

    float rs[4] = {};
    f32x4 O[4];
    #pragma unroll
    for (int dt = 0; dt < 4; dt++) O[dt] = (f32x4){0.f, 0.f, 0.f, 0.f};

    uint4 vp[2];
    uint2 bvv[4], bvn[4];

#define STAGE_K(j0, s) do {                                                   \
    _Pragma("unroll")                                                         \
    for (int l = 0; l < 2; l++) {                                             \
        int f = tid + (l << 8);                                               \
        int chunk = f >> 6, jr = f & 63;                                      \
        int krow = (j0) + jr; if (krow >= NTOK) krow = NTOK - 1;              \
        gl_lds16(Kg + ((size_t)(b * NTOK + krow)) * DIMC + h * HDIM + chunk * 8, \
                 &KsL[s][f * 8]);                                             \
    } } while (0)

#define LOAD_V(j0, dst) do {                                                  \
    _Pragma("unroll")                                                         \
    for (int l = 0; l < 2; l++) {                                             \
        int vrow = (j0) + vjr[l]; if (vrow >= NTOK) vrow = NTOK - 1;          \
        dst[l] = *(const uint4*)(Vg + ((size_t)(b * NTOK + vrow)) * DIMC      \
                                 + h * HDIM + vd0[l]);                        \
    } } while (0)

#define WRITE_V(src) do {                                                     \
    _Pragma("unroll")                                                         \
    for (int l = 0; l < 2; l++) {                                             \
        const u16* pe = (const u16*)&src[l];                                  \
        int jswz = vjr[l] ^ vd0[l];                                           \
        _Pragma("unroll")                                                     \
        for (int i = 0; i < 8; i++)                                           \
            VtL[(vd0[l] + i) * 72 + jswz] = pe[i];                            \
    } } while (0)

#define LOAD_B(j0, dst) do {                                                  \
    _Pragma("unroll")                                                         \
    for (int reg = 0; reg < 4; reg++)                                         \
        dst[reg] = *(const uint2*)(bp + boff[reg] + (j0));                    \
    } while (0)

    // prologue: tile 0
    STAGE_K(0, 0);
    LOAD_V(0, vp);
    LOAD_B(0, bvv);
    __syncthreads();        // drain: Ks[0] in LDS, vp loaded
    WRITE_V(vp);
    __syncthreads();        // VtL(0) visible

    for (int tt = 0; tt < 12; tt++) {
        const int p = tt & 1;
        if (tt < 11) {
            const int j0n = (tt + 1) << 6;
            STAGE_K(j0n, p ^ 1);     // Ks[p^1] readers finished at tt-1
            LOAD_V(j0n, vp);
            LOAD_B(j0n, bvn);
        }

        // V B-frags, b128 via swizzled offset
        bf16x8 bv[4][2];
        #pragma unroll
        for (int dt = 0; dt < 4; dt++) {
            int key8 = ((dt * 2 + (ln >> 3)) & 7) << 3;
            #pragma unroll
            for (int kp = 0; kp < 2; kp++) {
                int koff = (kp * 32 + (quad << 3)) ^ key8;
                bv[dt][kp] = *(const bf16x8*)&VtL[(dt * 16 + ln) * 72 + koff];
            }
        }

        // S = (Q*log2e/8) K^T - SMAX*log2e (via C-init)
        f32x4 s[4];
        #pragma unroll
        for (int nt = 0; nt < 4; nt++) s[nt] = (f32x4){NEGS, NEGS, NEGS, NEGS};
        __builtin_amdgcn_s_setprio(1);
        #pragma unroll
        for (int kp = 0; kp < 2; kp++)
            #pragma unroll
            for (int nt = 0; nt < 4; nt++) {
                bf16x8 bk = *(const bf16x8*)
                    &KsL[p][(((kp << 2) + quad) * 64 + nt * 16 + ln) * 8];
                s[nt] = __builtin_amdgcn_mfma_f32_16x16x32_bf16(aq[kp], bk, s[nt], 0, 0, 0);
            }
        __builtin_amdgcn_s_setprio(0);

        // p = exp2(s + b): 1 add + 1 native v_exp_f32 per element
        #pragma unroll
        for (int reg = 0; reg < 4; reg++) {
            uint2 bb = bvv[reg];
            float p0 = __builtin_exp2f(s[0][reg] + bflo(bb.x));
            float p1 = __builtin_exp2f(s[1][reg] + bfhi(bb.x));
            float p2 = __builtin_exp2f(s[2][reg] + bflo(bb.y));
            float p3 = __builtin_exp2f(s[3][reg] + bfhi(bb.y));
            s[0][reg] = p0; s[1][reg] = p1;
            s[2][reg] = p2; s[3][reg] = p3;
            rs[reg] += p0 + p1 + p2 + p3;
        }
        // P: C-layout -> A-layout through swizzled wave-private LDS
        u16* pwb = &Pw[w][0][0];
        #pragma unroll
        for (int nt = 0; nt < 4; nt++) {
            int colw = ((nt ^ quad) << 4) + ln;
            #pragma unroll
            for (int reg = 0; reg < 4; reg++)
                pwb[((quad << 2) + reg) * 72 + colw] = f2bf(s[nt][reg]);
        }
        bf16x8 ap[2];
        #pragma unroll
        for (int kp = 0; kp < 2; kp++) {
            int koff = (kp * 32 + (quad << 3)) ^ pswz;
            ap[kp] = *(const bf16x8*)&pwb[ln * 72 + koff];
        }
        // O += P V
        __builtin_amdgcn_s_setprio(1);
        #pragma unroll
        for (int dt = 0; dt < 4; dt++)
            #pragma unroll
            for (int kp = 0; kp < 2; kp++)
                O[dt] = __builtin_amdgcn_mfma_f32_16x16x32_bf16(
                    ap[kp], bv[dt][kp], O[dt], 0, 0, 0);
        __builtin_amdgcn_s_setprio(0);

        __syncthreads();    // readers of Ks[p]/VtL done; drains prefetches
                            // (covered by this tile's compute)
        if (tt < 11) {
            WRITE_V(vp);
            #pragma unroll
            for (int reg = 0; reg < 4; reg++) bvv[reg] = bvn[reg];
            __syncthreads();    // VtL(tt+1) visible
        }
    }

#undef STAGE_K
#undef LOAD_V
#undef WRITE_V
#undef LOAD_B

    // normalize + store
    #pragma unroll
    for (int reg = 0; reg < 4; reg++) {
        float t = rs[reg];
        #pragma unroll
        for (int mk = 8; mk >= 1; mk >>= 1) t += __shfl_xor(t, mk);
        float inv = 1.0f / t;
        int row = mbase + (quad << 2) + reg;
        if (row < NTOK) {
            #pragma unroll
            for (int dt = 0; dt < 4; dt++)
                ctx[((size_t)(b * NTOK + row)) * DIMC + h * HDIM + dt * 16 + ln]
                    = f2bf(O[dt][reg] * inv);
        }
    }
}

// ---------------------------------------------------------------------------
extern "C" void kernel_launch(void* const* d_in, const int* in_sizes, int n_in,
                              void* d_out, int out_size, void* d_ws, size_t ws_size,
                              hipStream_t stream)
{
    const float* x        = (const float*)d_in[0];
    const float* temp_q   = (const float*)d_in[1];
    const float* target_q = (const float*)d_in[2];
    const float* q_w      = (const float*)d_in[3];
    const float* k_w      = (const float*)d_in[4];
    const float* v_w      = (const float*)d_in[5];
    const float* proj_w   = (const float*)d_in[6];
    const float* proj_b   = (const float*)d_in[7];
    const float* rpb      = (const float*)d_in[8];
    const float* rpbt     = (const float*)d_in[9];
    const float* pw1      = (const float*)d_in[10];
    const float* pb1      = (const float*)d_in[11];
    const float* pw2      = (const float*)d_in[12];
    const float* pb2      = (const float*)d_in[13];
    const float* tab      = (const float*)d_in[14];
    const int*   tidx     = (const int*)d_in[15];
    const int*   gidx     = (const int*)d_in[16];
    float* out = (float*)d_out;

    char* ws = (char*)d_ws;
    const size_t S = (size_t)MROWS * DIMC * sizeof(u16);          // 18,186,240
    const size_t SZB = (size_t)NHEAD * NTOK * 768 * sizeof(u16);  // 13,639,680
    u16* CTX   = (u16*)(ws);
    u16* V     = (u16*)(ws + S);
    u16* Q     = (u16*)(ws + 2 * S);
    u16* K     = (u16*)(ws + 3 * S);
    u16* BIAS2 = (u16*)(ws + 4 * S);
    u16* WT    = (u16*)(ws + 4 * S + SZB);                        // 4 x 768 x 768

    prep_kernel<<<dim3(PREP_ALL), 256, 0, stream>>>(
        q_w, k_w, v_w, proj_w, WT,
        rpb, rpbt, tidx, gidx,
        pw1, pb1, pw2, pb2, tab, BIAS2);

    const u16* WTp = WT + 3 * (size_t)DIMC * DIMC;

    gemm_qkv<<<dim3(370), 512, 0, stream>>>(x, temp_q, target_q, WT, Q, K, V);
    attn_mfma<<<dim3(12, 12, 16), 256, 0, stream>>>(Q, K, V, BIAS2, CTX);
    gemm_proj<<<dim3(6, 185), 256, 0, stream>>>(CTX, WTp, proj_b, out);
}

// Round 11
// 480.585 us; speedup vs baseline: 1.2461x; 1.2461x over previous
//
#include <hip/hip_runtime.h>

// Convattn: B=16, N=740 (256+484), C=768, H=12, hd=64. Inputs/outputs fp32.
// R11: prep (MLP+TRW+bias) -> gemm_qkv (uniform planes, PROPER 2-phase:
// issue t+1 loads before compute t) -> attn (T14 issue-early) -> proj.
// ws layout CTX | V | Q | K | BIAS2 | WT. WT planes [q][k][v][p], q-plane
// pre-scaled 0.125*log2e; BIAS2 repacked [h][row][jb][ln][nt] pre-scaled
// log2e. Softmax = exp2(s+b), MFMA C-init -SMAX*log2e.

typedef unsigned short u16;
typedef short bf16x8 __attribute__((ext_vector_type(8)));
typedef float f32x4 __attribute__((ext_vector_type(4)));

#define BSZ   16
#define NTOK  740
#define NTMP  256
#define NTGT  484
#define DIMC  768
#define NHEAD 12
#define HDIM  64
#define MROWS (BSZ*NTOK)      // 11840
#define LOG2E 1.44269504f
#define NEGS  (-23.0831032f)  // -16 * log2e (fixed softmax max, scores ~|6|)

__device__ __forceinline__ float bflo(unsigned int u) {
    return __uint_as_float(u << 16);
}
__device__ __forceinline__ float bfhi(unsigned int u) {
    return __uint_as_float(u & 0xffff0000u);
}
__device__ __forceinline__ u16 f2bf(float f) {
    unsigned int u = __float_as_uint(f);
    u += 0x7fffu + ((u >> 16) & 1u);   // RNE
    return (u16)(u >> 16);
}

// async 16B global -> LDS (gfx950). LDS dest must be wave base + lane*16.
__device__ __forceinline__ void gl_lds16(const u16* g, u16* l) {
    __builtin_amdgcn_global_load_lds(
        (const __attribute__((address_space(1))) unsigned int*)(unsigned long long)g,
        (__attribute__((address_space(3))) unsigned int*)(unsigned int)(unsigned long long)l,
        16, 0, 0);
}

// repacked bias offset: [h][i][jb][ln][nt]
__device__ __forceinline__ size_t b2off(int h, int i, int j) {
    return ((size_t)(h * NTOK + i)) * 768 + ((j >> 6) << 6) + ((j & 15) << 2) + ((j >> 4) & 3);
}

// ---------------------------------------------------------------------------
// prep: MLP (first, long serial blocks overlap) + weight transpose + bias
// diagonal. grid = 484 + 576 + 2220 = 3280. (R9 body, unchanged.)
// ---------------------------------------------------------------------------
#define PREP_MLP  484
#define PREP_TRW  (PREP_MLP + 576)     // 1060
#define PREP_ALL  (PREP_TRW + 2220)    // 3280

__global__ __launch_bounds__(256) void prep_kernel(
    const float* __restrict__ w0, const float* __restrict__ w1,
    const float* __restrict__ w2, const float* __restrict__ w3,
    u16* __restrict__ Wt,
    const float* __restrict__ rpb, const float* __restrict__ rpbt,
    const int* __restrict__ tidx, const int* __restrict__ gidx,
    const float* __restrict__ pw1, const float* __restrict__ pb1,
    const float* __restrict__ pw2, const float* __restrict__ pb2,
    const float* __restrict__ tab, u16* __restrict__ bias)
{
    __shared__ float T[64][65];
    const int blk = blockIdx.x;
    const int tid = threadIdx.x;

    if (blk < PREP_MLP) {
        int g = blk;                      // 0..483
        int t = tid;                      // 0..255
        float a  = tab[(g * NTMP + t) * 2 + 0];
        float bb = tab[(g * NTMP + t) * 2 + 1];
        float acc[NHEAD];
        #pragma unroll
        for (int h = 0; h < NHEAD; h++) acc[h] = pb2[h];
        for (int k = 0; k < 512; k++) {
            float hid = fmaxf(a * pw1[k] + bb * pw1[512 + k] + pb1[k], 0.0f);
            #pragma unroll
            for (int h = 0; h < NHEAD; h++) acc[h] += hid * pw2[k * NHEAD + h];
        }
        #pragma unroll
        for (int h = 0; h < NHEAD; h++) {
            u16 v = f2bf(acc[h] * LOG2E);
            bias[b2off(h, t, NTMP + g)] = v;   // top-right
            bias[b2off(h, NTMP + g, t)] = v;   // bottom-left
        }
    } else if (blk < PREP_TRW) {
        int t = blk - PREP_MLP;           // 0..575
        int z = t / 144, rem = t - z * 144;
        int bx = rem % 12, by = rem / 12;
        const float* src = (z == 0) ? w0 : (z == 1) ? w1 : (z == 2) ? w2 : w3;
        const float scale = (z == 0) ? 0.125f * LOG2E : 1.0f;
        u16* dst = Wt + (size_t)z * DIMC * DIMC;
        int out0 = bx * 64, in0 = by * 64;
        #pragma unroll
        for (int l = 0; l < 4; l++) {
            int u = tid + (l << 8);
            int r = u >> 4, c4 = (u & 15) << 2;
            float4 p = *(const float4*)(src + (size_t)(in0 + r) * DIMC + out0 + c4);
            T[r][c4] = p.x; T[r][c4 + 1] = p.y; T[r][c4 + 2] = p.z; T[r][c4 + 3] = p.w;
        }
        __syncthreads();
        #pragma unroll
        for (int l = 0; l < 2; l++) {
            int u = tid + (l << 8);
            int r = u >> 3, c8 = (u & 7) << 3;
            u16 e[8];
            #pragma unroll
            for (int i = 0; i < 8; i++) e[i] = f2bf(T[c8 + i][r] * scale);
            *(uint4*)(dst + (size_t)(out0 + r) * DIMC + in0 + c8) = *(uint4*)e;
        }
    } else {
        int t = blk - PREP_TRW;           // 0..2219
        int jb = t % 3, i = t / 3;
        int j = jb * 256 + tid;
        u16 vals[NHEAD];
        if (j >= NTOK) {
            u16 neg = f2bf(-1e30f);
            #pragma unroll
            for (int h = 0; h < NHEAD; h++) vals[h] = neg;
        } else if (i < NTMP && j < NTMP) {
            int idx = tidx[i * NTMP + j];
            #pragma unroll
            for (int h = 0; h < NHEAD; h++) vals[h] = f2bf(rpbt[idx * NHEAD + h] * LOG2E);
        } else if (i >= NTMP && j >= NTMP) {
            int idx = gidx[(i - NTMP) * NTGT + (j - NTMP)];
            #pragma unroll
            for (int h = 0; h < NHEAD; h++) vals[h] = f2bf(rpb[idx * NHEAD + h] * LOG2E);
        } else {
            return;  // cross region
        }
        #pragma unroll
        for (int h = 0; h < NHEAD; h++) vals[h], bias[b2off(h, i, j)] = vals[h];
    }
}

// ---------------------------------------------------------------------------
// Fused QKV GEMM, UNIFORM blocks, PROPER 2-phase. grid (18, 185), BM=64,
// BK=64, BN=128. plane p = bx/6: 0=Q (A=tq/gq), 1=K, 2=V (A=x).
// Step t: issue A(t+1) fp32 loads -> regs AND B(t+1) gl_lds -> Bs[buf^1]
// BEFORE compute(buf); the post-compute __syncthreads drains loads that the
// 16-MFMA compute already covered (R9 exposed the full loaded latency between
// back-to-back barriers with compute after -> 15k cy/step). A written to LDS
// write-late (T14). A XOR-swizzled rows (rr^chunk), conflict-free (R9).
// LDS 8 + 2x16 = 40KB -> 4 blocks/CU (launch_bounds(256,4)).
// ---------------------------------------------------------------------------
__global__ __launch_bounds__(256, 4) void gemm_qkv(
    const float* __restrict__ x, const float* __restrict__ tq,
    const float* __restrict__ gq, const u16* __restrict__ Wt,
    u16* __restrict__ Qo, u16* __restrict__ Ko, u16* __restrict__ Vo)
{
    __shared__ __align__(16) u16 As[4096];      // [chunk(8)][row^chunk(64)][8] 8KB
    __shared__ __align__(16) u16 Bs[2][8192];   // [buf][chunk(8)][row(128)][8] 32KB
    const int tid = threadIdx.x;
    const int lane = tid & 63, w = tid >> 6;
    const int quad = lane >> 4, ln = lane & 15;

    // XCD-chunked bijective swizzle.
    const int nwg = 18 * 185;
    const int flat = blockIdx.y * 18 + blockIdx.x;
    const int q = nwg >> 3, r = nwg & 7;
    const int xcd = flat & 7, sidx = flat >> 3;
    const int wg = (xcd < r) ? xcd * (q + 1) + sidx
                             : r * (q + 1) + (xcd - r) * q + sidx;
    const int by = wg / 18, bx = wg - by * 18;

    const int m0 = by << 6;                       // BM = 64
    const int wm = (w >> 1) << 5, wn = (w & 1) << 6;

    const int p = (bx < 6) ? 0 : (bx < 12) ? 1 : 2;
    const int nn = (bx - p * 6) << 7;
    const u16* Wb = Wt + (size_t)p * DIMC * DIMC + (size_t)nn * DIMC;
    u16* Co = (p == 0) ? Qo : (p == 1) ? Ko : Vo;

    // per-thread A staging geometry: row rr, col-quarter qq
    const int rr = tid >> 2, qq = tid & 3;
    const int arow = m0 + rr;
    const float* aptr;
    if (p == 0) {
        int b = arow / NTOK, n = arow - b * NTOK;
        aptr = (n < NTMP)
             ? tq + ((size_t)(b * NTMP + n)) * DIMC
             : gq + ((size_t)(b * NTGT + (n - NTMP))) * DIMC;
    } else {
        aptr = x + (size_t)arow * DIMC;
    }
    // swizzled write offsets (chunk = 2qq+c, physical row = rr ^ chunk)
    const int wof0 = ((2 * qq + 0) * 64 + (rr ^ (2 * qq + 0))) * 8;
    const int wof1 = ((2 * qq + 1) * 64 + (rr ^ (2 * qq + 1))) * 8;

    float4 a0, a1, a2, a3;    // in-flight A(t+1), held across compute

#define LOADA(t) do {                                                         \
    const float* s_ = aptr + ((t) << 6) + (qq << 4);                          \
    a0 = ((const float4*)s_)[0]; a1 = ((const float4*)s_)[1];                 \
    a2 = ((const float4*)s_)[2]; a3 = ((const float4*)s_)[3];                 \
    } while (0)

#define WRITEA() do {                                                         \
    u16 e_[16] = {f2bf(a0.x), f2bf(a0.y), f2bf(a0.z), f2bf(a0.w),             \
                  f2bf(a1.x), f2bf(a1.y), f2bf(a1.z), f2bf(a1.w),             \
                  f2bf(a2.x), f2bf(a2.y), f2bf(a2.z), f2bf(a2.w),             \
                  f2bf(a3.x), f2bf(a3.y), f2bf(a3.z), f2bf(a3.w)};            \
    *(uint4*)&As[wof0] = ((uint4*)e_)[0];                                     \
    *(uint4*)&As[wof1] = ((uint4*)e_)[1];                                     \
    } while (0)

#define STAGEB(t, s) do {                                                     \
    _Pragma("unroll")                                                         \
    for (int l = 0; l < 4; l++) {                                             \
        int f = tid + (l << 8);                                               \
        int c8 = f >> 7, r2 = f & 127;                                        \
        gl_lds16(Wb + (size_t)r2 * DIMC + ((t) << 6) + c8 * 8, &Bs[s][f * 8]); \
    } } while (0)

    f32x4 acc[2][4];
    #pragma unroll
    for (int i = 0; i < 2; i++)
        #pragma unroll
        for (int j = 0; j < 4; j++) acc[i][j] = (f32x4){0.f, 0.f, 0.f, 0.f};

    // prologue: tile 0
    LOADA(0);
    STAGEB(0, 0);
    __syncthreads();          // drains vmcnt: B(0) in LDS, A(0) in regs
    WRITEA();
    __syncthreads();          // As(0) visible

    int buf = 0;
    #pragma unroll 1
    for (int t = 0; t < 12; t++) {
        if (t < 11) {
            LOADA(t + 1);
            STAGEB(t + 1, buf ^ 1);
        }
        #pragma unroll
        for (int kp = 0; kp < 2; kp++) {
            const int kc0 = (kp << 2) + quad;          // chunk for this quad
            bf16x8 af[2], bfr[4];
            #pragma unroll
            for (int mt = 0; mt < 2; mt++)
                af[mt] = *(const bf16x8*)
                    &As[(kc0 * 64 + ((wm + mt * 16 + ln) ^ kc0)) * 8];
            #pragma unroll
            for (int nt = 0; nt < 4; nt++)
                bfr[nt] = *(const bf16x8*)
                    &Bs[buf][(kc0 * 128 + wn + nt * 16 + ln) * 8];
            #pragma unroll
            for (int mt = 0; mt < 2; mt++)
                #pragma unroll
                for (int nt = 0; nt < 4; nt++)
                    acc[mt][nt] = __builtin_amdgcn_mfma_f32_16x16x32_bf16(
                        af[mt], bfr[nt], acc[mt][nt], 0, 0, 0);
        }
        if (t < 11) {
            __syncthreads();  // As readers done; drains vmcnt -> B(t+1), A(t+1)
            WRITEA();         // As(t+1)
            __syncthreads();  // As(t+1) visible
            buf ^= 1;
        }
    }
#undef LOADA
#undef WRITEA
#undef STAGEB

    #pragma unroll
    for (int mt = 0; mt < 2; mt++)
        #pragma unroll
        for (int reg = 0; reg < 4; reg++) {
            int grow = m0 + wm + mt * 16 + (quad << 2) + reg;
            #pragma unroll
            for (int nt = 0; nt < 4; nt++)
                Co[(size_t)grow * DIMC + nn + wn + nt * 16 + ln]
                    = f2bf(acc[mt][nt][reg]);
        }
}

// ---------------------------------------------------------------------------
// proj GEMM: BM=64, BN=128, A = CTX bf16 via gl_lds, fp32 out + bias.
// grid (6, 185), single-buffered, XCD swizzle. (R9 body, unchanged.)
// ---------------------------------------------------------------------------
__global__ __launch_bounds__(256) void gemm_proj(
    const u16* __restrict__ A, const u16* __restrict__ Wt,
    const float* __restrict__ pb, float* __restrict__ Cf)
{
    __shared__ __align__(16) u16 As[4096];   // 8KB
    __shared__ __align__(16) u16 Bs[8192];   // 16KB
    const int tid = threadIdx.x;
    const int lane = tid & 63, w = tid >> 6;
    const int quad = lane >> 4, ln = lane & 15;

    const int nwg = 6 * 185;
    const int flat = blockIdx.y * 6 + blockIdx.x;
    const int q = nwg >> 3, r = nwg & 7;
    const int xcd = flat & 7, sidx = flat >> 3;
    const int wg = (xcd < r) ? xcd * (q + 1) + sidx
                             : r * (q + 1) + (xcd - r) * q + sidx;
    const int by = wg / 6, bx = wg - by * 6;

    const int m0 = by << 6;
    const int wm = (w >> 1) << 5, wn = (w & 1) << 6;
    const int nn = bx << 7;
    const u16* Wb = Wt + (size_t)nn * DIMC;

    f32x4 acc[2][4];
    #pragma unroll
    for (int i = 0; i < 2; i++)
        #pragma unroll
        for (int j = 0; j < 4; j++) acc[i][j] = (f32x4){0.f, 0.f, 0.f, 0.f};

    #pragma unroll 1
    for (int t = 0; t < 12; t++) {
        __syncthreads();
        const int k0 = t << 6;
        #pragma unroll
        for (int l = 0; l < 2; l++) {
            int f = tid + (l << 8);
            int c8 = f >> 6, r2 = f & 63;
            gl_lds16(A + (size_t)(m0 + r2) * DIMC + k0 + c8 * 8, &As[f * 8]);
        }
        #pragma unroll
        for (int l = 0; l < 4; l++) {
            int f = tid + (l << 8);
            int c8 = f >> 7, r2 = f & 127;
            gl_lds16(Wb + (size_t)r2 * DIMC + k0 + c8 * 8, &Bs[f * 8]);
        }
        __syncthreads();
        #pragma unroll
        for (int kp = 0; kp < 2; kp++) {
            bf16x8 af[2], bfr[4];
            #pragma unroll
            for (int mt = 0; mt < 2; mt++)
                af[mt] = *(const bf16x8*)
                    &As[(((kp << 2) + quad) * 64 + wm + mt * 16 + ln) * 8];
            #pragma unroll
            for (int nt = 0; nt < 4; nt++)
                bfr[nt] = *(const bf16x8*)
                    &Bs[(((kp << 2) + quad) * 128 + wn + nt * 16 + ln) * 8];
            #pragma unroll
            for (int mt = 0; mt < 2; mt++)
                #pragma unroll
                for (int nt = 0; nt < 4; nt++)
                    acc[mt][nt] = __builtin_amdgcn_mfma_f32_16x16x32_bf16(
                        af[mt], bfr[nt], acc[mt][nt], 0, 0, 0);
        }
    }

    #pragma unroll
    for (int mt = 0; mt < 2; mt++)
        #pragma unroll
        for (int reg = 0; reg < 4; reg++) {
            int grow = m0 + wm + mt * 16 + (quad << 2) + reg;
            #pragma unroll
            for (int nt = 0; nt < 4; nt++) {
                int gcol = nn + wn + nt * 16 + ln;
                Cf[(size_t)grow * DIMC + gcol] = acc[mt][nt][reg] + pb[gcol];
            }
        }
}

// ---------------------------------------------------------------------------
// Flash MFMA attention, T14 issue-early/write-late (R10 body, first clean
// read this round). 64 Q-rows/block, 4 waves; grid 2304, h-major XCD remap.
// K double-buffered; V/bias -> regs issued before compute. LDS 34.8KB ->
// 4 blocks/CU. exp2 softmax, C-init -SMAX*log2e.
// ---------------------------------------------------------------------------
__global__ __launch_bounds__(256) void attn_mfma(
    const u16* __restrict__ Qg, const u16* __restrict__ Kg,
    const u16* __restrict__ Vg, const u16* __restrict__ bias,
    u16* __restrict__ ctx)
{
    __shared__ __align__(16) u16 KsL[2][4096];     // [buf][chunk(8)][jr(64)][8]
    __shared__ __align__(16) u16 VtL[64 * 72];     // [d][j^swz], stride 72
    __shared__ __align__(16) u16 Pw[4][16][72];    // [w][m][k^swz]

    const int tid = threadIdx.x;
    const int lane = tid & 63, w = tid >> 6;
    const int quad = lane >> 4, ln = lane & 15;

    // h-major XCD-chunked remap (bijective: 2304 = 8 * 288).
    const int flat = (blockIdx.z * 12 + blockIdx.y) * 12 + blockIdx.x;
    const int wg = (flat & 7) * 288 + (flat >> 3);
    const int h = wg / 192;
    const int rem = wg - h * 192;
    const int b = rem / 12;
    const int q0 = (rem - b * 12) << 6;

    const int mbase = q0 + (w << 4);               // wave's 16 rows
    const u16* bp = bias + ((size_t)h * NTOK) * 768;

    // Q fragments (A-layout), held for the whole kernel
    bf16x8 aq[2];
    {
        int qrow = mbase + ln; if (qrow >= NTOK) qrow = NTOK - 1;
        #pragma unroll
        for (int kp = 0; kp < 2; kp++)
            aq[kp] = *(const bf16x8*)(Qg + ((size_t)(b * NTOK + qrow)) * DIMC
                                      + h * HDIM + kp * 32 + (quad << 3));
    }
    int boff[4];
    #pragma unroll
    for (int reg = 0; reg < 4; reg++) {
        int rr = mbase + (quad << 2) + reg;
        if (rr >= NTOK) rr = NTOK - 1;
        boff[reg] = rr * 768 + (ln << 2);
    }

    // V staging geometry (per thread, fixed)
    int vjr[2], vd0[2];
    #pragma unroll
    for (int l = 0; l < 2; l++) {
        int u = tid + (l << 8);
        vjr[l] = u >> 3; vd0[l] = (u & 7) << 3;
    }

    // P read swizzle constant (row = ln)
    const int pswz = ((ln >> 2) & 3) << 4;

    float rs[4] = {};
    f32x4 O[4];
    #pragma unroll
    for (int dt = 0; dt < 4; dt++) O[dt] = (f32x4){0.f, 0.f, 0.f, 0.f};

    uint4 vp[2];
    uint2 bvv[4], bvn[4];

#define STAGE_K(j0, s) do {                                                   \
    _Pragma("unroll")                                                         \
    for (int l = 0; l < 2; l++) {                                             \
        int f = tid + (l << 8);                                               \
        int chunk = f >> 6, jr = f & 63;                                      \
        int krow = (j0) + jr; if (krow >= NTOK) krow = NTOK - 1;              \
        gl_lds16(Kg + ((size_t)(b * NTOK + krow)) * DIMC + h * HDIM + chunk * 8, \
                 &KsL[s][f * 8]);                                             \
    } } while (0)

#define LOAD_V(j0, dst) do {                                                  \
    _Pragma("unroll")                                                         \
    for (int l = 0; l < 2; l++) {                                             \
        int vrow = (j0) + vjr[l]; if (vrow >= NTOK) vrow = NTOK - 1;          \
        dst[l] = *(const uint4*)(Vg + ((size_t)(b * NTOK + vrow)) * DIMC      \
                                 + h * HDIM + vd0[l]);                        \
    } } while (0)

#define WRITE_V(src) do {                                                     \
    _Pragma("unroll")                                                         \
    for (int l = 0; l < 2; l++) {                                             \
        const u16* pe = (const u16*)&src[l];                                  \
        int jswz = vjr[l] ^ vd0[l];                                           \
        _Pragma("unroll")                                                     \
        for (int i = 0; i < 8; i++)                                           \
            VtL[(vd0[l] + i) * 72 + jswz] = pe[i];                            \
    } } while (0)

#define LOAD_B(j0, dst) do {                                                  \
    _Pragma("unroll")                                                         \
    for (int reg = 0; reg < 4; reg++)                                         \
        dst[reg] = *(const uint2*)(bp + boff[reg] + (j0));                    \
    } while (0)

    // prologue: tile 0
    STAGE_K(0, 0);
    LOAD_V(0, vp);
    LOAD_B(0, bvv);
    __syncthreads();        // drain: Ks[0] in LDS, vp loaded
    WRITE_V(vp);
    __syncthreads();        // VtL(0) visible

    for (int tt = 0; tt < 12; tt++) {
        const int p = tt & 1;
        if (tt < 11) {
            const int j0n = (tt + 1) << 6;
            STAGE_K(j0n, p ^ 1);     // Ks[p^1] readers finished at tt-1
            LOAD_V(j0n, vp);
            LOAD_B(j0n, bvn);
        }

        // V B-frags, b128 via swizzled offset
        bf16x8 bv[4][2];
        #pragma unroll
        for (int dt = 0; dt < 4; dt++) {
            int key8 = ((dt * 2 + (ln >> 3)) & 7) << 3;
            #pragma unroll
            for (int kp = 0; kp < 2; kp++) {
                int koff = (kp * 32 + (quad << 3)) ^ key8;
                bv[dt][kp] = *(const bf16x8*)&VtL[(dt * 16 + ln) * 72 + koff];
            }
        }

        // S = (Q*log2e/8) K^T - SMAX*log2e (via C-init)
        f32x4 s[4];
        #pragma unroll
        for (int nt = 0; nt < 4; nt++) s[nt] = (f32x4){NEGS, NEGS, NEGS, NEGS};
        __builtin_amdgcn_s_setprio(1);
        #pragma unroll
        for (int kp = 0; kp < 2; kp++)
            #pragma unroll
            for (int nt = 0; nt < 4; nt++) {
                bf16x8 bk = *(const bf16x8*)
                    &KsL[p][(((kp << 2) + quad) * 64 + nt * 16 + ln) * 8];
                s[nt] = __builtin_amdgcn_mfma_f32_16x16x32_bf16(aq[kp], bk, s[nt], 0, 0, 0);
            }
        __builtin_amdgcn_s_setprio(0);

        // p = exp2(s + b): 1 add + 1 native v_exp_f32 per element
        #pragma unroll
        for (int reg = 0; reg < 4; reg++) {
            uint2 bb = bvv[reg];
            float p0 = __builtin_exp2f(s[0][reg] + bflo(bb.x));
            float p1 = __builtin_exp2f(s[1][reg] + bfhi(bb.x));
            float p2 = __builtin_exp2f(s[2][reg] + bflo(bb.y));
            float p3 = __builtin_exp2f(s[3][reg] + bfhi(bb.y));
            s[0][reg] = p0; s[1][reg] = p1;
            s[2][reg] = p2; s[3][reg] = p3;
            rs[reg] += p0 + p1 + p2 + p3;
        }
        // P: C-layout -> A-layout through swizzled wave-private LDS
        u16* pwb = &Pw[w][0][0];
        #pragma unroll
        for (int nt = 0; nt < 4; nt++) {
            int colw = ((nt ^ quad) << 4) + ln;
            #pragma unroll
            for (int reg = 0; reg < 4; reg++)
                pwb[((quad << 2) + reg) * 72 + colw] = f2bf(s[nt][reg]);
        }
        bf16x8 ap[2];
        #pragma unroll
        for (int kp = 0; kp < 2; kp++) {
            int koff = (kp * 32 + (quad << 3)) ^ pswz;
            ap[kp] = *(const bf16x8*)&pwb[ln * 72 + koff];
        }
        // O += P V
        __builtin_amdgcn_s_setprio(1);
        #pragma unroll
        for (int dt = 0; dt < 4; dt++)
            #pragma unroll
            for (int kp = 0; kp < 2; kp++)
                O[dt] = __builtin_amdgcn_mfma_f32_16x16x32_bf16(
                    ap[kp], bv[dt][kp], O[dt], 0, 0, 0);
        __builtin_amdgcn_s_setprio(0);

        __syncthreads();    // readers of Ks[p]/VtL done; drains prefetches
                            // (covered by this tile's compute)
        if (tt < 11) {
            WRITE_V(vp);
            #pragma unroll
            for (int reg = 0; reg < 4; reg++) bvv[reg] = bvn[reg];
            __syncthreads();    // VtL(tt+1) visible
        }
    }

#undef STAGE_K
#undef LOAD_V
#undef WRITE_V
#undef LOAD_B

    // normalize + store
    #pragma unroll
    for (int reg = 0; reg < 4; reg++) {
        float t = rs[reg];
        #pragma unroll
        for (int mk = 8; mk >= 1; mk >>= 1) t += __shfl_xor(t, mk);
        float inv = 1.0f / t;
        int row = mbase + (quad << 2) + reg;
        if (row < NTOK) {
            #pragma unroll
            for (int dt = 0; dt < 4; dt++)
                ctx[((size_t)(b * NTOK + row)) * DIMC + h * HDIM + dt * 16 + ln]
                    = f2bf(O[dt][reg] * inv);
        }
    }
}

// ---------------------------------------------------------------------------
extern "C" void kernel_launch(void* const* d_in, const int* in_sizes, int n_in,
                              void* d_out, int out_size, void* d_ws, size_t ws_size,
                              hipStream_t stream)
{
    const float* x        = (const float*)d_in[0];
    const float* temp_q   = (const float*)d_in[1];
    const float* target_q = (const float*)d_in[2];
    const float* q_w      = (const float*)d_in[3];
    const float* k_w      = (const float*)d_in[4];
    const float* v_w      = (const float*)d_in[5];
    const float* proj_w   = (const float*)d_in[6];
    const float* proj_b   = (const float*)d_in[7];
    const float* rpb      = (const float*)d_in[8];
    const float* rpbt     = (const float*)d_in[9];
    const float* pw1      = (const float*)d_in[10];
    const float* pb1      = (const float*)d_in[11];
    const float* pw2      = (const float*)d_in[12];
    const float* pb2      = (const float*)d_in[13];
    const float* tab      = (const float*)d_in[14];
    const int*   tidx     = (const int*)d_in[15];
    const int*   gidx     = (const int*)d_in[16];
    float* out = (float*)d_out;

    char* ws = (char*)d_ws;
    const size_t S = (size_t)MROWS * DIMC * sizeof(u16);          // 18,186,240
    const size_t SZB = (size_t)NHEAD * NTOK * 768 * sizeof(u16);  // 13,639,680
    u16* CTX   = (u16*)(ws);
    u16* V     = (u16*)(ws + S);
    u16* Q     = (u16*)(ws + 2 * S);
    u16* K     = (u16*)(ws + 3 * S);
    u16* BIAS2 = (u16*)(ws + 4 * S);
    u16* WT    = (u16*)(ws + 4 * S + SZB);                        // 4 x 768 x 768

    prep_kernel<<<dim3(PREP_ALL), 256, 0, stream>>>(
        q_w, k_w, v_w, proj_w, WT,
        rpb, rpbt, tidx, gidx,
        pw1, pb1, pw2, pb2, tab, BIAS2);

    const u16* WTp = WT + 3 * (size_t)DIMC * DIMC;

    gemm_qkv<<<dim3(18, 185), 256, 0, stream>>>(x, temp_q, target_q, WT, Q, K, V);
    attn_mfma<<<dim3(12, 12, 16), 256, 0, stream>>>(Q, K, V, BIAS2, CTX);
    gemm_proj<<<dim3(6, 185), 256, 0, stream>>>(CTX, WTp, proj_b, out);
}

// Round 12
// 472.751 us; speedup vs baseline: 1.2668x; 1.0166x over previous
//
#include <hip/hip_runtime.h>

// Convattn: B=16, N=740 (256+484), C=768, H=12, hd=64. Inputs/outputs fp32.
// R12: prep (MLP+TRW+bias) -> gemm_qkv (R11 2-phase, uniform planes) ->
// attn (R7 single-buffered body, 6 blocks/CU) -> proj (R5-era 128x128 DB).
// ws layout CTX | V | Q | K | BIAS2 | WT. WT planes [q][k][v][p], q-plane
// pre-scaled 0.125*log2e; BIAS2 repacked [h][row][jb][ln][nt] pre-scaled
// log2e. Softmax = exp2(s+b), MFMA C-init -SMAX*log2e.

typedef unsigned short u16;
typedef short bf16x8 __attribute__((ext_vector_type(8)));
typedef float f32x4 __attribute__((ext_vector_type(4)));

#define BSZ   16
#define NTOK  740
#define NTMP  256
#define NTGT  484
#define DIMC  768
#define NHEAD 12
#define HDIM  64
#define MROWS (BSZ*NTOK)      // 11840
#define LOG2E 1.44269504f
#define NEGS  (-23.0831032f)  // -16 * log2e (fixed softmax max, scores ~|6|)

__device__ __forceinline__ float bflo(unsigned int u) {
    return __uint_as_float(u << 16);
}
__device__ __forceinline__ float bfhi(unsigned int u) {
    return __uint_as_float(u & 0xffff0000u);
}
__device__ __forceinline__ u16 f2bf(float f) {
    unsigned int u = __float_as_uint(f);
    u += 0x7fffu + ((u >> 16) & 1u);   // RNE
    return (u16)(u >> 16);
}

// async 16B global -> LDS (gfx950). LDS dest must be wave base + lane*16.
__device__ __forceinline__ void gl_lds16(const u16* g, u16* l) {
    __builtin_amdgcn_global_load_lds(
        (const __attribute__((address_space(1))) unsigned int*)(unsigned long long)g,
        (__attribute__((address_space(3))) unsigned int*)(unsigned int)(unsigned long long)l,
        16, 0, 0);
}

// repacked bias offset: [h][i][jb][ln][nt]
__device__ __forceinline__ size_t b2off(int h, int i, int j) {
    return ((size_t)(h * NTOK + i)) * 768 + ((j >> 6) << 6) + ((j & 15) << 2) + ((j >> 4) & 3);
}

// ---------------------------------------------------------------------------
// prep: MLP (first, long serial blocks overlap) + weight transpose + bias
// diagonal. grid = 484 + 576 + 2220 = 3280.
// ---------------------------------------------------------------------------
#define PREP_MLP  484
#define PREP_TRW  (PREP_MLP + 576)     // 1060
#define PREP_ALL  (PREP_TRW + 2220)    // 3280

__global__ __launch_bounds__(256) void prep_kernel(
    const float* __restrict__ w0, const float* __restrict__ w1,
    const float* __restrict__ w2, const float* __restrict__ w3,
    u16* __restrict__ Wt,
    const float* __restrict__ rpb, const float* __restrict__ rpbt,
    const int* __restrict__ tidx, const int* __restrict__ gidx,
    const float* __restrict__ pw1, const float* __restrict__ pb1,
    const float* __restrict__ pw2, const float* __restrict__ pb2,
    const float* __restrict__ tab, u16* __restrict__ bias)
{
    __shared__ float T[64][65];
    const int blk = blockIdx.x;
    const int tid = threadIdx.x;

    if (blk < PREP_MLP) {
        int g = blk;                      // 0..483
        int t = tid;                      // 0..255
        float a  = tab[(g * NTMP + t) * 2 + 0];
        float bb = tab[(g * NTMP + t) * 2 + 1];
        float acc[NHEAD];
        #pragma unroll
        for (int h = 0; h < NHEAD; h++) acc[h] = pb2[h];
        for (int k = 0; k < 512; k++) {
            float hid = fmaxf(a * pw1[k] + bb * pw1[512 + k] + pb1[k], 0.0f);
            #pragma unroll
            for (int h = 0; h < NHEAD; h++) acc[h] += hid * pw2[k * NHEAD + h];
        }
        #pragma unroll
        for (int h = 0; h < NHEAD; h++) {
            u16 v = f2bf(acc[h] * LOG2E);
            bias[b2off(h, t, NTMP + g)] = v;   // top-right
            bias[b2off(h, NTMP + g, t)] = v;   // bottom-left
        }
    } else if (blk < PREP_TRW) {
        int t = blk - PREP_MLP;           // 0..575
        int z = t / 144, rem = t - z * 144;
        int bx = rem % 12, by = rem / 12;
        const float* src = (z == 0) ? w0 : (z == 1) ? w1 : (z == 2) ? w2 : w3;
        const float scale = (z == 0) ? 0.125f * LOG2E : 1.0f;
        u16* dst = Wt + (size_t)z * DIMC * DIMC;
        int out0 = bx * 64, in0 = by * 64;
        #pragma unroll
        for (int l = 0; l < 4; l++) {
            int u = tid + (l << 8);
            int r = u >> 4, c4 = (u & 15) << 2;
            float4 p = *(const float4*)(src + (size_t)(in0 + r) * DIMC + out0 + c4);
            T[r][c4] = p.x; T[r][c4 + 1] = p.y; T[r][c4 + 2] = p.z; T[r][c4 + 3] = p.w;
        }
        __syncthreads();
        #pragma unroll
        for (int l = 0; l < 2; l++) {
            int u = tid + (l << 8);
            int r = u >> 3, c8 = (u & 7) << 3;
            u16 e[8];
            #pragma unroll
            for (int i = 0; i < 8; i++) e[i] = f2bf(T[c8 + i][r] * scale);
            *(uint4*)(dst + (size_t)(out0 + r) * DIMC + in0 + c8) = *(uint4*)e;
        }
    } else {
        int t = blk - PREP_TRW;           // 0..2219
        int jb = t % 3, i = t / 3;
        int j = jb * 256 + tid;
        u16 vals[NHEAD];
        if (j >= NTOK) {
            u16 neg = f2bf(-1e30f);
            #pragma unroll
            for (int h = 0; h < NHEAD; h++) vals[h] = neg;
        } else if (i < NTMP && j < NTMP) {
            int idx = tidx[i * NTMP + j];
            #pragma unroll
            for (int h = 0; h < NHEAD; h++) vals[h] = f2bf(rpbt[idx * NHEAD + h] * LOG2E);
        } else if (i >= NTMP && j >= NTMP) {
            int idx = gidx[(i - NTMP) * NTGT + (j - NTMP)];
            #pragma unroll
            for (int h = 0; h < NHEAD; h++) vals[h] = f2bf(rpb[idx * NHEAD + h] * LOG2E);
        } else {
            return;  // cross region
        }
        #pragma unroll
        for (int h = 0; h < NHEAD; h++) bias[b2off(h, i, j)] = vals[h];
    }
}

// ---------------------------------------------------------------------------
// Fused QKV GEMM (R11 body, unchanged). grid (18, 185), BM=64, BK=64, BN=128.
// plane p = bx/6: 0=Q (A=tq/gq), 1=K, 2=V (A=x). Proper 2-phase: issue A(t+1)
// regs + B(t+1) gl_lds before compute(t). A XOR-swizzled rows (rr^chunk).
// LDS 8 + 2x16 = 40KB -> 4 blocks/CU.
// ---------------------------------------------------------------------------
__global__ __launch_bounds__(256, 4) void gemm_qkv(
    const float* __restrict__ x, const float* __restrict__ tq,
    const float* __restrict__ gq, const u16* __restrict__ Wt,
    u16* __restrict__ Qo, u16* __restrict__ Ko, u16* __restrict__ Vo)
{
    __shared__ __align__(16) u16 As[4096];      // [chunk(8)][row^chunk(64)][8] 8KB
    __shared__ __align__(16) u16 Bs[2][8192];   // [buf][chunk(8)][row(128)][8] 32KB
    const int tid = threadIdx.x;
    const int lane = tid & 63, w = tid >> 6;
    const int quad = lane >> 4, ln = lane & 15;

    // XCD-chunked bijective swizzle.
    const int nwg = 18 * 185;
    const int flat = blockIdx.y * 18 + blockIdx.x;
    const int q = nwg >> 3, r = nwg & 7;
    const int xcd = flat & 7, sidx = flat >> 3;
    const int wg = (xcd < r) ? xcd * (q + 1) + sidx
                             : r * (q + 1) + (xcd - r) * q + sidx;
    const int by = wg / 18, bx = wg - by * 18;

    const int m0 = by << 6;                       // BM = 64
    const int wm = (w >> 1) << 5, wn = (w & 1) << 6;

    const int p = (bx < 6) ? 0 : (bx < 12) ? 1 : 2;
    const int nn = (bx - p * 6) << 7;
    const u16* Wb = Wt + (size_t)p * DIMC * DIMC + (size_t)nn * DIMC;
    u16* Co = (p == 0) ? Qo : (p == 1) ? Ko : Vo;

    // per-thread A staging geometry: row rr, col-quarter qq
    const int rr = tid >> 2, qq = tid & 3;
    const int arow = m0 + rr;
    const float* aptr;
    if (p == 0) {
        int b = arow / NTOK, n = arow - b * NTOK;
        aptr = (n < NTMP)
             ? tq + ((size_t)(b * NTMP + n)) * DIMC
             : gq + ((size_t)(b * NTGT + (n - NTMP))) * DIMC;
    } else {
        aptr = x + (size_t)arow * DIMC;
    }
    // swizzled write offsets (chunk = 2qq+c, physical row = rr ^ chunk)
    const int wof0 = ((2 * qq + 0) * 64 + (rr ^ (2 * qq + 0))) * 8;
    const int wof1 = ((2 * qq + 1) * 64 + (rr ^ (2 * qq + 1))) * 8;

    float4 a0, a1, a2, a3;    // in-flight A(t+1), held across compute

#define LOADA(t) do {                                                         \
    const float* s_ = aptr + ((t) << 6) + (qq << 4);                          \
    a0 = ((const float4*)s_)[0]; a1 = ((const float4*)s_)[1];                 \
    a2 = ((const float4*)s_)[2]; a3 = ((const float4*)s_)[3];                 \
    } while (0)

#define WRITEA() do {                                                         \
    u16 e_[16] = {f2bf(a0.x), f2bf(a0.y), f2bf(a0.z), f2bf(a0.w),             \
                  f2bf(a1.x), f2bf(a1.y), f2bf(a1.z), f2bf(a1.w),             \
                  f2bf(a2.x), f2bf(a2.y), f2bf(a2.z), f2bf(a2.w),             \
                  f2bf(a3.x), f2bf(a3.y), f2bf(a3.z), f2bf(a3.w)};            \
    *(uint4*)&As[wof0] = ((uint4*)e_)[0];                                     \
    *(uint4*)&As[wof1] = ((uint4*)e_)[1];                                     \
    } while (0)

#define STAGEB(t, s) do {                                                     \
    _Pragma("unroll")                                                         \
    for (int l = 0; l < 4; l++) {                                             \
        int f = tid + (l << 8);                                               \
        int c8 = f >> 7, r2 = f & 127;                                        \
        gl_lds16(Wb + (size_t)r2 * DIMC + ((t) << 6) + c8 * 8, &Bs[s][f * 8]); \
    } } while (0)

    f32x4 acc[2][4];
    #pragma unroll
    for (int i = 0; i < 2; i++)
        #pragma unroll
        for (int j = 0; j < 4; j++) acc[i][j] = (f32x4){0.f, 0.f, 0.f, 0.f};

    // prologue: tile 0
    LOADA(0);
    STAGEB(0, 0);
    __syncthreads();          // drains vmcnt: B(0) in LDS, A(0) in regs
    WRITEA();
    __syncthreads();          // As(0) visible

    int buf = 0;
    #pragma unroll 1
    for (int t = 0; t < 12; t++) {
        if (t < 11) {
            LOADA(t + 1);
            STAGEB(t + 1, buf ^ 1);
        }
        #pragma unroll
        for (int kp = 0; kp < 2; kp++) {
            const int kc0 = (kp << 2) + quad;          // chunk for this quad
            bf16x8 af[2], bfr[4];
            #pragma unroll
            for (int mt = 0; mt < 2; mt++)
                af[mt] = *(const bf16x8*)
                    &As[(kc0 * 64 + ((wm + mt * 16 + ln) ^ kc0)) * 8];
            #pragma unroll
            for (int nt = 0; nt < 4; nt++)
                bfr[nt] = *(const bf16x8*)
                    &Bs[buf][(kc0 * 128 + wn + nt * 16 + ln) * 8];
            #pragma unroll
            for (int mt = 0; mt < 2; mt++)
                #pragma unroll
                for (int nt = 0; nt < 4; nt++)
                    acc[mt][nt] = __builtin_amdgcn_mfma_f32_16x16x32_bf16(
                        af[mt], bfr[nt], acc[mt][nt], 0, 0, 0);
        }
        if (t < 11) {
            __syncthreads();  // As readers done; drains vmcnt -> B(t+1), A(t+1)
            WRITEA();         // As(t+1)
            __syncthreads();  // As(t+1) visible
            buf ^= 1;
        }
    }
#undef LOADA
#undef WRITEA
#undef STAGEB

    #pragma unroll
    for (int mt = 0; mt < 2; mt++)
        #pragma unroll
        for (int reg = 0; reg < 4; reg++) {
            int grow = m0 + wm + mt * 16 + (quad << 2) + reg;
            #pragma unroll
            for (int nt = 0; nt < 4; nt++)
                Co[(size_t)grow * DIMC + nn + wn + nt * 16 + ln]
                    = f2bf(acc[mt][nt][reg]);
        }
}

// ---------------------------------------------------------------------------
// proj GEMM: R5-era 128x128, BK=64, 2-phase double-buffered, gl_lds both
// operands. grid (6, 93), row clamp (93*128 > 11840). fp32 out + bias.
// Bijective XCD-chunked swizzle.
// ---------------------------------------------------------------------------
__global__ __launch_bounds__(256) void gemm_proj(
    const u16* __restrict__ A, const u16* __restrict__ Wt,
    const float* __restrict__ pb, float* __restrict__ Cf)
{
    __shared__ __align__(16) u16 As[2][8192];   // [buf][chunk(8)][row(128)][8]
    __shared__ __align__(16) u16 Bs[2][8192];
    const int tid = threadIdx.x;
    const int lane = tid & 63, w = tid >> 6;
    const int quad = lane >> 4, ln = lane & 15;

    const int nwg = 6 * 93;
    const int flat = blockIdx.y * 6 + blockIdx.x;
    const int q = nwg >> 3, r = nwg & 7;
    const int xcd = flat & 7, sidx = flat >> 3;
    const int wg = (xcd < r) ? xcd * (q + 1) + sidx
                             : r * (q + 1) + (xcd - r) * q + sidx;
    const int by = wg / 6, bx = wg - by * 6;

    const int m0 = by << 7;
    const int wm = (w >> 1) << 6, wn = (w & 1) << 6;
    const int nn = bx << 7;
    const u16* Wb = Wt + (size_t)nn * DIMC;

    f32x4 acc[4][4];
    #pragma unroll
    for (int i = 0; i < 4; i++)
        #pragma unroll
        for (int j = 0; j < 4; j++)
            acc[i][j] = (f32x4){0.f, 0.f, 0.f, 0.f};

#define STAGE(s, k0) do {                                                     \
    _Pragma("unroll")                                                         \
    for (int l = 0; l < 4; l++) {                                             \
        int f = tid + (l << 8);          /* 0..1023 */                        \
        int c8 = f >> 7, rr = f & 127;                                        \
        int grow = m0 + rr; if (grow >= MROWS) grow = MROWS - 1;              \
        gl_lds16(A + (size_t)grow * DIMC + (k0) + c8 * 8, &As[s][f * 8]);     \
        gl_lds16(Wb + (size_t)rr * DIMC + (k0) + c8 * 8, &Bs[s][f * 8]);      \
    } } while (0)

#define COMPUTE(s) do {                                                       \
    _Pragma("unroll")                                                         \
    for (int kp = 0; kp < 2; kp++) {                                          \
        bf16x8 af[4], bfr[4];                                                 \
        _Pragma("unroll")                                                     \
        for (int mt = 0; mt < 4; mt++)                                        \
            af[mt] = *(const bf16x8*)                                         \
                &As[s][(((kp << 2) + quad) * 128 + wm + mt * 16 + ln) * 8];   \
        _Pragma("unroll")                                                     \
        for (int nt = 0; nt < 4; nt++)                                        \
            bfr[nt] = *(const bf16x8*)                                        \
                &Bs[s][(((kp << 2) + quad) * 128 + wn + nt * 16 + ln) * 8];   \
        _Pragma("unroll")                                                     \
        for (int mt = 0; mt < 4; mt++)                                        \
            _Pragma("unroll")                                                 \
            for (int nt = 0; nt < 4; nt++)                                    \
                acc[mt][nt] = __builtin_amdgcn_mfma_f32_16x16x32_bf16(        \
                    af[mt], bfr[nt], acc[mt][nt], 0, 0, 0);                   \
    } } while (0)

    STAGE(0, 0);
    __syncthreads();
    #pragma unroll 1
    for (int t = 0; t < 12; t += 2) {
        STAGE(1, (t + 1) << 6);
        COMPUTE(0);
        __syncthreads();
        if (t < 10) STAGE(0, (t + 2) << 6);
        COMPUTE(1);
        __syncthreads();
    }

#undef STAGE
#undef COMPUTE

    #pragma unroll
    for (int mt = 0; mt < 4; mt++) {
        #pragma unroll
        for (int reg = 0; reg < 4; reg++) {
            int grow = m0 + wm + mt * 16 + (quad << 2) + reg;
            if (grow >= MROWS) continue;
            #pragma unroll
            for (int nt = 0; nt < 4; nt++) {
                int gcol = nn + wn + nt * 16 + ln;
                Cf[(size_t)grow * DIMC + gcol] = acc[mt][nt][reg] + pb[gcol];
            }
        }
    }
}

// ---------------------------------------------------------------------------
// Flash MFMA attention (R7/R9 single-buffered body — 26.6KB, 6 blocks/CU;
// T14 K-dbuf reverted: it cost occupancy 6->4 and +18us). 64 Q-rows/block,
// 4 waves; grid 2304, h-major XCD remap. exp2 softmax, C-init -SMAX*log2e.
// ---------------------------------------------------------------------------
__global__ __launch_bounds__(256) void attn_mfma(
    const u16* __restrict__ Qg, const u16* __restrict__ Kg,
    const u16* __restrict__ Vg, const u16* __restrict__ bias,
    u16* __restrict__ ctx)
{
    __shared__ __align__(16) u16 KsL[4096];        // [chunk(8)][jr(64)][8]
    __shared__ __align__(16) u16 VtL[64 * 72];     // [d][j^swz], stride 72
    __shared__ __align__(16) u16 Pw[4][16][72];    // [w][m][k^swz]

    const int tid = threadIdx.x;
    const int lane = tid & 63, w = tid >> 6;
    const int quad = lane >> 4, ln = lane & 15;

    // h-major XCD-chunked remap (bijective: 2304 = 8 * 288).
    const int flat = (blockIdx.z * 12 + blockIdx.y) * 12 + blockIdx.x;
    const int wg = (flat & 7) * 288 + (flat >> 3);
    const int h = wg / 192;
    const int rem = wg - h * 192;
    const int b = rem / 12;
    const int q0 = (rem - b * 12) << 6;

    const int mbase = q0 + (w << 4);               // wave's 16 rows
    const u16* bp = bias + ((size_t)h * NTOK) * 768;

    // Q fragments (A-layout), held for the whole kernel
    bf16x8 aq[2];
    {
        int qrow = mbase + ln; if (qrow >= NTOK) qrow = NTOK - 1;
        #pragma unroll
        for (int kp = 0; kp < 2; kp++)
            aq[kp] = *(const bf16x8*)(Qg + ((size_t)(b * NTOK + qrow)) * DIMC
                                      + h * HDIM + kp * 32 + (quad << 3));
    }
    int boff[4];
    #pragma unroll
    for (int reg = 0; reg < 4; reg++) {
        int rr = mbase + (quad << 2) + reg;
        if (rr >= NTOK) rr = NTOK - 1;
        boff[reg] = rr * 768 + (ln << 2);
    }

    // P read swizzle constant (row = ln)
    const int pswz = ((ln >> 2) & 3) << 4;

    float rs[4] = {};
    f32x4 O[4];
    #pragma unroll
    for (int dt = 0; dt < 4; dt++) O[dt] = (f32x4){0.f, 0.f, 0.f, 0.f};

    for (int j0 = 0; j0 < NTOK; j0 += 64) {
        __syncthreads();
        // K tile via async global->LDS, chunk-major
        #pragma unroll
        for (int l = 0; l < 2; l++) {
            int f = tid + (l << 8);                // 0..511
            int chunk = f >> 6, jr = f & 63;
            int krow = j0 + jr; if (krow >= NTOK) krow = NTOK - 1;
            gl_lds16(Kg + ((size_t)(b * NTOK + krow)) * DIMC + h * HDIM + chunk * 8,
                     KsL + f * 8);
        }
        // bias prefetch into registers
        uint2 bvv[4];
        #pragma unroll
        for (int reg = 0; reg < 4; reg++)
            bvv[reg] = *(const uint2*)(bp + boff[reg] + j0);
        // V tile transposed into XOR-swizzled LDS: elem V^T[d][j] at
        // d*72 + (j ^ ((d>>3)&7)*8)
        #pragma unroll
        for (int l = 0; l < 2; l++) {
            int u = tid + (l << 8);
            int jr = u >> 3, d0 = (u & 7) << 3;
            int vrow = j0 + jr; if (vrow >= NTOK) vrow = NTOK - 1;
            uint4 p = *(const uint4*)(Vg + ((size_t)(b * NTOK + vrow)) * DIMC + h * HDIM + d0);
            const u16* pe = (const u16*)&p;
            int jswz = jr ^ d0;                   // key = d0 (multiple of 8, <64)
            #pragma unroll
            for (int i = 0; i < 8; i++) VtL[(d0 + i) * 72 + jswz] = pe[i];
        }
        __syncthreads();

        // V B-frags, b128 via swizzled offset
        bf16x8 bv[4][2];
        #pragma unroll
        for (int dt = 0; dt < 4; dt++) {
            int key8 = ((dt * 2 + (ln >> 3)) & 7) << 3;
            #pragma unroll
            for (int kp = 0; kp < 2; kp++) {
                int koff = (kp * 32 + (quad << 3)) ^ key8;
                bv[dt][kp] = *(const bf16x8*)&VtL[(dt * 16 + ln) * 72 + koff];
            }
        }

        // S = (Q*log2e/8) K^T - SMAX*log2e (via C-init)
        f32x4 s[4];
        #pragma unroll
        for (int nt = 0; nt < 4; nt++) s[nt] = (f32x4){NEGS, NEGS, NEGS, NEGS};
        __builtin_amdgcn_s_setprio(1);
        #pragma unroll
        for (int kp = 0; kp < 2; kp++)
            #pragma unroll
            for (int nt = 0; nt < 4; nt++) {
                bf16x8 bk = *(const bf16x8*)
                    &KsL[(((kp << 2) + quad) * 64 + nt * 16 + ln) * 8];
                s[nt] = __builtin_amdgcn_mfma_f32_16x16x32_bf16(aq[kp], bk, s[nt], 0, 0, 0);
            }
        __builtin_amdgcn_s_setprio(0);

        // p = exp2(s + b): 1 add + 1 native v_exp_f32 per element
        #pragma unroll
        for (int reg = 0; reg < 4; reg++) {
            uint2 bb = bvv[reg];
            float p0 = __builtin_exp2f(s[0][reg] + bflo(bb.x));
            float p1 = __builtin_exp2f(s[1][reg] + bfhi(bb.x));
            float p2 = __builtin_exp2f(s[2][reg] + bflo(bb.y));
            float p3 = __builtin_exp2f(s[3][reg] + bfhi(bb.y));
            s[0][reg] = p0; s[1][reg] = p1;
            s[2][reg] = p2; s[3][reg] = p3;
            rs[reg] += p0 + p1 + p2 + p3;
        }
        // P: C-layout -> A-layout through swizzled wave-private LDS
        u16* pwb = &Pw[w][0][0];
        #pragma unroll
        for (int nt = 0; nt < 4; nt++) {
            int colw = ((nt ^ quad) << 4) + ln;
            #pragma unroll
            for (int reg = 0; reg < 4; reg++)
                pwb[((quad << 2) + reg) * 72 + colw] = f2bf(s[nt][reg]);
        }
        bf16x8 ap[2];
        #pragma unroll
        for (int kp = 0; kp < 2; kp++) {
            int koff = (kp * 32 + (quad << 3)) ^ pswz;
            ap[kp] = *(const bf16x8*)&pwb[ln * 72 + koff];
        }
        // O += P V
        __builtin_amdgcn_s_setprio(1);
        #pragma unroll
        for (int dt = 0; dt < 4; dt++)
            #pragma unroll
            for (int kp = 0; kp < 2; kp++)
                O[dt] = __builtin_amdgcn_mfma_f32_16x16x32_bf16(
                    ap[kp], bv[dt][kp], O[dt], 0, 0, 0);
        __builtin_amdgcn_s_setprio(0);
    }

    // normalize + store
    #pragma unroll
    for (int reg = 0; reg < 4; reg++) {
        float t = rs[reg];
        #pragma unroll
        for (int mk = 8; mk >= 1; mk >>= 1) t += __shfl_xor(t, mk);
        float inv = 1.0f / t;
        int row = mbase + (quad << 2) + reg;
        if (row < NTOK) {
            #pragma unroll
            for (int dt = 0; dt < 4; dt++)
                ctx[((size_t)(b * NTOK + row)) * DIMC + h * HDIM + dt * 16 + ln]
                    = f2bf(O[dt][reg] * inv);
        }
    }
}

// ---------------------------------------------------------------------------
extern "C" void kernel_launch(void* const* d_in, const int* in_sizes, int n_in,
                              void* d_out, int out_size, void* d_ws, size_t ws_size,
                              hipStream_t stream)
{
    const float* x        = (const float*)d_in[0];
    const float* temp_q   = (const float*)d_in[1];
    const float* target_q = (const float*)d_in[2];
    const float* q_w      = (const float*)d_in[3];
    const float* k_w      = (const float*)d_in[4];
    const float* v_w      = (const float*)d_in[5];
    const float* proj_w   = (const float*)d_in[6];
    const float* proj_b   = (const float*)d_in[7];
    const float* rpb      = (const float*)d_in[8];
    const float* rpbt     = (const float*)d_in[9];
    const float* pw1      = (const float*)d_in[10];
    const float* pb1      = (const float*)d_in[11];
    const float* pw2      = (const float*)d_in[12];
    const float* pb2      = (const float*)d_in[13];
    const float* tab      = (const float*)d_in[14];
    const int*   tidx     = (const int*)d_in[15];
    const int*   gidx     = (const int*)d_in[16];
    float* out = (float*)d_out;

    char* ws = (char*)d_ws;
    const size_t S = (size_t)MROWS * DIMC * sizeof(u16);          // 18,186,240
    const size_t SZB = (size_t)NHEAD * NTOK * 768 * sizeof(u16);  // 13,639,680
    u16* CTX   = (u16*)(ws);
    u16* V     = (u16*)(ws + S);
    u16* Q     = (u16*)(ws + 2 * S);
    u16* K     = (u16*)(ws + 3 * S);
    u16* BIAS2 = (u16*)(ws + 4 * S);
    u16* WT    = (u16*)(ws + 4 * S + SZB);                        // 4 x 768 x 768

    prep_kernel<<<dim3(PREP_ALL), 256, 0, stream>>>(
        q_w, k_w, v_w, proj_w, WT,
        rpb, rpbt, tidx, gidx,
        pw1, pb1, pw2, pb2, tab, BIAS2);

    const u16* WTp = WT + 3 * (size_t)DIMC * DIMC;

    gemm_qkv<<<dim3(18, 185), 256, 0, stream>>>(x, temp_q, target_q, WT, Q, K, V);
    attn_mfma<<<dim3(12, 12, 16), 256, 0, stream>>>(Q, K, V, BIAS2, CTX);
    gemm_proj<<<dim3(6, 93), 256, 0, stream>>>(CTX, WTp, proj_b, out);
}

// Round 13
// 465.319 us; speedup vs baseline: 1.2870x; 1.0160x over previous
//
#include <hip/hip_runtime.h>

// Convattn: B=16, N=740 (256+484), C=768, H=12, hd=64. Inputs/outputs fp32.
// R13: prep (MLP + x->bf16 conv + TRW + bias, 5500 blocks — R5-proven shape)
// -> gemm_qkv (uniform planes; Q: inline-conv A from tq/gq; K/V: bf16 XB via
// gl_lds, A+B double-buffered, ONE barrier/K-step) -> attn (R7 body) ->
// proj (128x128 DB). ws: XB(=CTX alias) | V | Q | K | BIAS2 | WT.
// WT planes [q][k][v][p], q-plane pre-scaled 0.125*log2e; BIAS2 repacked
// [h][row][jb][ln][nt] pre-scaled log2e. Softmax = exp2(s+b), C-init
// -SMAX*log2e.

typedef unsigned short u16;
typedef short bf16x8 __attribute__((ext_vector_type(8)));
typedef float f32x4 __attribute__((ext_vector_type(4)));

#define BSZ   16
#define NTOK  740
#define NTMP  256
#define NTGT  484
#define DIMC  768
#define NHEAD 12
#define HDIM  64
#define MROWS (BSZ*NTOK)      // 11840
#define LOG2E 1.44269504f
#define NEGS  (-23.0831032f)  // -16 * log2e (fixed softmax max, scores ~|6|)

__device__ __forceinline__ float bflo(unsigned int u) {
    return __uint_as_float(u << 16);
}
__device__ __forceinline__ float bfhi(unsigned int u) {
    return __uint_as_float(u & 0xffff0000u);
}
__device__ __forceinline__ u16 f2bf(float f) {
    unsigned int u = __float_as_uint(f);
    u += 0x7fffu + ((u >> 16) & 1u);   // RNE
    return (u16)(u >> 16);
}

// async 16B global -> LDS (gfx950). LDS dest must be wave base + lane*16.
__device__ __forceinline__ void gl_lds16(const u16* g, u16* l) {
    __builtin_amdgcn_global_load_lds(
        (const __attribute__((address_space(1))) unsigned int*)(unsigned long long)g,
        (__attribute__((address_space(3))) unsigned int*)(unsigned int)(unsigned long long)l,
        16, 0, 0);
}

// repacked bias offset: [h][i][jb][ln][nt]
__device__ __forceinline__ size_t b2off(int h, int i, int j) {
    return ((size_t)(h * NTOK + i)) * 768 + ((j >> 6) << 6) + ((j & 15) << 2) + ((j >> 4) & 3);
}

// ---------------------------------------------------------------------------
// prep: MLP (first) + x->bf16 conv (2 chunks/thread) + weight transpose +
// bias diagonal. grid = 484 + 2220 + 576 + 2220 = 5500 (R5-proven shape:
// the 5016 BW blocks behind the MLP give it an overlap shadow).
// ---------------------------------------------------------------------------
#define PREP_MLP  484
#define PREP_CONV (PREP_MLP + 2220)    // 2704
#define PREP_TRW  (PREP_CONV + 576)    // 3280
#define PREP_ALL  (PREP_TRW + 2220)    // 5500

__global__ __launch_bounds__(256) void prep_kernel(
    const float* __restrict__ x, u16* __restrict__ XB,
    const float* __restrict__ w0, const float* __restrict__ w1,
    const float* __restrict__ w2, const float* __restrict__ w3,
    u16* __restrict__ Wt,
    const float* __restrict__ rpb, const float* __restrict__ rpbt,
    const int* __restrict__ tidx, const int* __restrict__ gidx,
    const float* __restrict__ pw1, const float* __restrict__ pb1,
    const float* __restrict__ pw2, const float* __restrict__ pb2,
    const float* __restrict__ tab, u16* __restrict__ bias)
{
    __shared__ float T[64][65];
    const int blk = blockIdx.x;
    const int tid = threadIdx.x;

    if (blk < PREP_MLP) {
        // ----- cross-bias MLP -----
        int g = blk;                      // 0..483
        int t = tid;                      // 0..255
        float a  = tab[(g * NTMP + t) * 2 + 0];
        float bb = tab[(g * NTMP + t) * 2 + 1];
        float acc[NHEAD];
        #pragma unroll
        for (int h = 0; h < NHEAD; h++) acc[h] = pb2[h];
        for (int k = 0; k < 512; k++) {
            float hid = fmaxf(a * pw1[k] + bb * pw1[512 + k] + pb1[k], 0.0f);
            #pragma unroll
            for (int h = 0; h < NHEAD; h++) acc[h] += hid * pw2[k * NHEAD + h];
        }
        #pragma unroll
        for (int h = 0; h < NHEAD; h++) {
            u16 v = f2bf(acc[h] * LOG2E);
            bias[b2off(h, t, NTMP + g)] = v;   // top-right
            bias[b2off(h, NTMP + g, t)] = v;   // bottom-left
        }
    } else if (blk < PREP_CONV) {
        // ----- x fp32 -> bf16 (XB), 2 chunks/thread -----
        int t0 = (blk - PREP_MLP) * 512 + tid;
        int t1 = t0 + 256;
        const float* s0 = x + (size_t)t0 * 8;
        const float* s1 = x + (size_t)t1 * 8;
        float4 a0 = ((const float4*)s0)[0], a1 = ((const float4*)s0)[1];
        float4 b0 = ((const float4*)s1)[0], b1 = ((const float4*)s1)[1];
        {
            u16 e[8] = {f2bf(a0.x), f2bf(a0.y), f2bf(a0.z), f2bf(a0.w),
                        f2bf(a1.x), f2bf(a1.y), f2bf(a1.z), f2bf(a1.w)};
            *(uint4*)(XB + (size_t)t0 * 8) = *(uint4*)e;
        }
        {
            u16 e[8] = {f2bf(b0.x), f2bf(b0.y), f2bf(b0.z), f2bf(b0.w),
                        f2bf(b1.x), f2bf(b1.y), f2bf(b1.z), f2bf(b1.w)};
            *(uint4*)(XB + (size_t)t1 * 8) = *(uint4*)e;
        }
    } else if (blk < PREP_TRW) {
        // ----- weight transpose + bf16 (z=0 scaled log2e/8) -----
        int t = blk - PREP_CONV;          // 0..575
        int z = t / 144, rem = t - z * 144;
        int bx = rem % 12, by = rem / 12;
        const float* src = (z == 0) ? w0 : (z == 1) ? w1 : (z == 2) ? w2 : w3;
        const float scale = (z == 0) ? 0.125f * LOG2E : 1.0f;
        u16* dst = Wt + (size_t)z * DIMC * DIMC;
        int out0 = bx * 64, in0 = by * 64;
        #pragma unroll
        for (int l = 0; l < 4; l++) {
            int u = tid + (l << 8);
            int r = u >> 4, c4 = (u & 15) << 2;
            float4 p = *(const float4*)(src + (size_t)(in0 + r) * DIMC + out0 + c4);
            T[r][c4] = p.x; T[r][c4 + 1] = p.y; T[r][c4 + 2] = p.z; T[r][c4 + 3] = p.w;
        }
        __syncthreads();
        #pragma unroll
        for (int l = 0; l < 2; l++) {
            int u = tid + (l << 8);
            int r = u >> 3, c8 = (u & 7) << 3;
            u16 e[8];
            #pragma unroll
            for (int i = 0; i < 8; i++) e[i] = f2bf(T[c8 + i][r] * scale);
            *(uint4*)(dst + (size_t)(out0 + r) * DIMC + in0 + c8) = *(uint4*)e;
        }
    } else {
        // ----- bias diagonal blocks + padding (scaled log2e) -----
        int t = blk - PREP_TRW;           // 0..2219
        int jb = t % 3, i = t / 3;
        int j = jb * 256 + tid;
        u16 vals[NHEAD];
        if (j >= NTOK) {
            u16 neg = f2bf(-1e30f);
            #pragma unroll
            for (int h = 0; h < NHEAD; h++) vals[h] = neg;
        } else if (i < NTMP && j < NTMP) {
            int idx = tidx[i * NTMP + j];
            #pragma unroll
            for (int h = 0; h < NHEAD; h++) vals[h] = f2bf(rpbt[idx * NHEAD + h] * LOG2E);
        } else if (i >= NTMP && j >= NTMP) {
            int idx = gidx[(i - NTMP) * NTGT + (j - NTMP)];
            #pragma unroll
            for (int h = 0; h < NHEAD; h++) vals[h] = f2bf(rpb[idx * NHEAD + h] * LOG2E);
        } else {
            return;  // cross region
        }
        #pragma unroll
        for (int h = 0; h < NHEAD; h++) bias[b2off(h, i, j)] = vals[h];
    }
}

// ---------------------------------------------------------------------------
// Fused QKV GEMM, uniform planes. grid (18, 185), BM=64, BK=64, BN=128.
// p = bx/6: 0=Q, 1=K, 2=V.
// Q path: A = tq/gq fp32, inline f2bf reg-staged (R11 path: 3 barriers/step).
// K/V paths: A = XB bf16 via gl_lds16, A+B BOTH double-buffered -> issue
// stage(t+1) before compute(t), ONE barrier per K-step, half the A-bytes.
// Shared-memory union SH[2][12288]: [s][0..4095]=A buf s, [s][4096..]=B buf s.
// LDS 48KB -> 3 blocks/CU. Bijective XCD-chunked swizzle.
// ---------------------------------------------------------------------------
__global__ __launch_bounds__(256, 3) void gemm_qkv(
    const float* __restrict__ tq, const float* __restrict__ gq,
    const u16* __restrict__ XB, const u16* __restrict__ Wt,
    u16* __restrict__ Qo, u16* __restrict__ Ko, u16* __restrict__ Vo)
{
    __shared__ __align__(16) u16 SH[2][12288];   // 48KB
    const int tid = threadIdx.x;
    const int lane = tid & 63, w = tid >> 6;
    const int quad = lane >> 4, ln = lane & 15;

    // XCD-chunked bijective swizzle.
    const int nwg = 18 * 185;
    const int flat = blockIdx.y * 18 + blockIdx.x;
    const int q = nwg >> 3, r = nwg & 7;
    const int xcd = flat & 7, sidx = flat >> 3;
    const int wg = (xcd < r) ? xcd * (q + 1) + sidx
                             : r * (q + 1) + (xcd - r) * q + sidx;
    const int by = wg / 18, bx = wg - by * 18;

    const int m0 = by << 6;                       // BM = 64
    const int wm = (w >> 1) << 5, wn = (w & 1) << 6;

    const int p = (bx < 6) ? 0 : (bx < 12) ? 1 : 2;
    const int nn = (bx - p * 6) << 7;
    const u16* Wb = Wt + (size_t)p * DIMC * DIMC + (size_t)nn * DIMC;
    u16* Co = (p == 0) ? Qo : (p == 1) ? Ko : Vo;

#define BS(s) (&SH[s][4096])
#define STAGEB(t, s) do {                                                     \
    _Pragma("unroll")                                                         \
    for (int l = 0; l < 4; l++) {                                             \
        int f = tid + (l << 8);                                               \
        int c8 = f >> 7, r2 = f & 127;                                        \
        gl_lds16(Wb + (size_t)r2 * DIMC + ((t) << 6) + c8 * 8, BS(s) + f * 8); \
    } } while (0)

    f32x4 acc[2][4];
    #pragma unroll
    for (int i = 0; i < 2; i++)
        #pragma unroll
        for (int j = 0; j < 4; j++) acc[i][j] = (f32x4){0.f, 0.f, 0.f, 0.f};

    if (p == 0) {
        // ================= Q path: inline conv, reg-staged A =================
        u16* Asq = &SH[0][0];             // 8KB, single-buffered, swizzled rows
        const int rr = tid >> 2, qq = tid & 3;
        const int arow = m0 + rr;
        int b = arow / NTOK, n = arow - b * NTOK;
        const float* aptr = (n < NTMP)
                          ? tq + ((size_t)(b * NTMP + n)) * DIMC
                          : gq + ((size_t)(b * NTGT + (n - NTMP))) * DIMC;
        const int wof0 = ((2 * qq + 0) * 64 + (rr ^ (2 * qq + 0))) * 8;
        const int wof1 = ((2 * qq + 1) * 64 + (rr ^ (2 * qq + 1))) * 8;
        float4 a0, a1, a2, a3;

#define LOADA(t) do {                                                         \
    const float* s_ = aptr + ((t) << 6) + (qq << 4);                          \
    a0 = ((const float4*)s_)[0]; a1 = ((const float4*)s_)[1];                 \
    a2 = ((const float4*)s_)[2]; a3 = ((const float4*)s_)[3];                 \
    } while (0)

#define WRITEA() do {                                                         \
    u16 e_[16] = {f2bf(a0.x), f2bf(a0.y), f2bf(a0.z), f2bf(a0.w),             \
                  f2bf(a1.x), f2bf(a1.y), f2bf(a1.z), f2bf(a1.w),             \
                  f2bf(a2.x), f2bf(a2.y), f2bf(a2.z), f2bf(a2.w),             \
                  f2bf(a3.x), f2bf(a3.y), f2bf(a3.z), f2bf(a3.w)};            \
    *(uint4*)&Asq[wof0] = ((uint4*)e_)[0];                                    \
    *(uint4*)&Asq[wof1] = ((uint4*)e_)[1];                                    \
    } while (0)

        LOADA(0);
        STAGEB(0, 0);
        __syncthreads();
        WRITEA();
        __syncthreads();

        int buf = 0;
        #pragma unroll 1
        for (int t = 0; t < 12; t++) {
            if (t < 11) {
                LOADA(t + 1);
                STAGEB(t + 1, buf ^ 1);
            }
            #pragma unroll
            for (int kp = 0; kp < 2; kp++) {
                const int kc0 = (kp << 2) + quad;
                bf16x8 af[2], bfr[4];
                #pragma unroll
                for (int mt = 0; mt < 2; mt++)
                    af[mt] = *(const bf16x8*)
                        &Asq[(kc0 * 64 + ((wm + mt * 16 + ln) ^ kc0)) * 8];
                #pragma unroll
                for (int nt = 0; nt < 4; nt++)
                    bfr[nt] = *(const bf16x8*)
                        &BS(buf)[(kc0 * 128 + wn + nt * 16 + ln) * 8];
                #pragma unroll
                for (int mt = 0; mt < 2; mt++)
                    #pragma unroll
                    for (int nt = 0; nt < 4; nt++)
                        acc[mt][nt] = __builtin_amdgcn_mfma_f32_16x16x32_bf16(
                            af[mt], bfr[nt], acc[mt][nt], 0, 0, 0);
            }
            if (t < 11) {
                __syncthreads();
                WRITEA();
                __syncthreads();
                buf ^= 1;
            }
        }
#undef LOADA
#undef WRITEA
    } else {
        // ============ K/V paths: bf16 XB via gl_lds, 1 barrier/step ==========
        const u16* Ab = XB + (size_t)m0 * DIMC;

#define ASK(s) (&SH[s][0])
#define STAGEA(t, s) do {                                                     \
    _Pragma("unroll")                                                         \
    for (int l = 0; l < 2; l++) {                                             \
        int f = tid + (l << 8);                                               \
        int c8 = f >> 6, r2 = f & 63;                                         \
        gl_lds16(Ab + (size_t)r2 * DIMC + ((t) << 6) + c8 * 8, ASK(s) + f * 8); \
    } } while (0)

        STAGEA(0, 0);
        STAGEB(0, 0);
        __syncthreads();      // drains vmcnt(0): tile 0 ready

        int buf = 0;
        #pragma unroll 1
        for (int t = 0; t < 12; t++) {
            if (t < 11) {
                STAGEA(t + 1, buf ^ 1);
                STAGEB(t + 1, buf ^ 1);
            }
            #pragma unroll
            for (int kp = 0; kp < 2; kp++) {
                const int kc0 = (kp << 2) + quad;
                bf16x8 af[2], bfr[4];
                #pragma unroll
                for (int mt = 0; mt < 2; mt++)
                    af[mt] = *(const bf16x8*)
                        &ASK(buf)[(kc0 * 64 + wm + mt * 16 + ln) * 8];
                #pragma unroll
                for (int nt = 0; nt < 4; nt++)
                    bfr[nt] = *(const bf16x8*)
                        &BS(buf)[(kc0 * 128 + wn + nt * 16 + ln) * 8];
                #pragma unroll
                for (int mt = 0; mt < 2; mt++)
                    #pragma unroll
                    for (int nt = 0; nt < 4; nt++)
                        acc[mt][nt] = __builtin_amdgcn_mfma_f32_16x16x32_bf16(
                            af[mt], bfr[nt], acc[mt][nt], 0, 0, 0);
            }
            __syncthreads();  // readers of buf done + buf^1 staging drained
            buf ^= 1;
        }
#undef ASK
#undef STAGEA
    }
#undef BS
#undef STAGEB

    #pragma unroll
    for (int mt = 0; mt < 2; mt++)
        #pragma unroll
        for (int reg = 0; reg < 4; reg++) {
            int grow = m0 + wm + mt * 16 + (quad << 2) + reg;
            #pragma unroll
            for (int nt = 0; nt < 4; nt++)
                Co[(size_t)grow * DIMC + nn + wn + nt * 16 + ln]
                    = f2bf(acc[mt][nt][reg]);
        }
}

// ---------------------------------------------------------------------------
// proj GEMM: 128x128, BK=64, 2-phase double-buffered, gl_lds both operands.
// grid (6, 93), row clamp. fp32 out + bias. (R12 body, unchanged.)
// ---------------------------------------------------------------------------
__global__ __launch_bounds__(256) void gemm_proj(
    const u16* __restrict__ A, const u16* __restrict__ Wt,
    const float* __restrict__ pb, float* __restrict__ Cf)
{
    __shared__ __align__(16) u16 As[2][8192];   // [buf][chunk(8)][row(128)][8]
    __shared__ __align__(16) u16 Bs[2][8192];
    const int tid = threadIdx.x;
    const int lane = tid & 63, w = tid >> 6;
    const int quad = lane >> 4, ln = lane & 15;

    const int nwg = 6 * 93;
    const int flat = blockIdx.y * 6 + blockIdx.x;
    const int q = nwg >> 3, r = nwg & 7;
    const int xcd = flat & 7, sidx = flat >> 3;
    const int wg = (xcd < r) ? xcd * (q + 1) + sidx
                             : r * (q + 1) + (xcd - r) * q + sidx;
    const int by = wg / 6, bx = wg - by * 6;

    const int m0 = by << 7;
    const int wm = (w >> 1) << 6, wn = (w & 1) << 6;
    const int nn = bx << 7;
    const u16* Wb = Wt + (size_t)nn * DIMC;

    f32x4 acc[4][4];
    #pragma unroll
    for (int i = 0; i < 4; i++)
        #pragma unroll
        for (int j = 0; j < 4; j++)
            acc[i][j] = (f32x4){0.f, 0.f, 0.f, 0.f};

#define STAGE(s, k0) do {                                                     \
    _Pragma("unroll")                                                         \
    for (int l = 0; l < 4; l++) {                                             \
        int f = tid + (l << 8);          /* 0..1023 */                        \
        int c8 = f >> 7, rr = f & 127;                                        \
        int grow = m0 + rr; if (grow >= MROWS) grow = MROWS - 1;              \
        gl_lds16(A + (size_t)grow * DIMC + (k0) + c8 * 8, &As[s][f * 8]);     \
        gl_lds16(Wb + (size_t)rr * DIMC + (k0) + c8 * 8, &Bs[s][f * 8]);      \
    } } while (0)

#define COMPUTE(s) do {                                                       \
    _Pragma("unroll")                                                         \
    for (int kp = 0; kp < 2; kp++) {                                          \
        bf16x8 af[4], bfr[4];                                                 \
        _Pragma("unroll")                                                     \
        for (int mt = 0; mt < 4; mt++)                                        \
            af[mt] = *(const bf16x8*)                                         \
                &As[s][(((kp << 2) + quad) * 128 + wm + mt * 16 + ln) * 8];   \
        _Pragma("unroll")                                                     \
        for (int nt = 0; nt < 4; nt++)                                        \
            bfr[nt] = *(const bf16x8*)                                        \
                &Bs[s][(((kp << 2) + quad) * 128 + wn + nt * 16 + ln) * 8];   \
        _Pragma("unroll")                                                     \
        for (int mt = 0; mt < 4; mt++)                                        \
            _Pragma("unroll")                                                 \
            for (int nt = 0; nt < 4; nt++)                                    \
                acc[mt][nt] = __builtin_amdgcn_mfma_f32_16x16x32_bf16(        \
                    af[mt], bfr[nt], acc[mt][nt], 0, 0, 0);                   \
    } } while (0)

    STAGE(0, 0);
    __syncthreads();
    #pragma unroll 1
    for (int t = 0; t < 12; t += 2) {
        STAGE(1, (t + 1) << 6);
        COMPUTE(0);
        __syncthreads();
        if (t < 10) STAGE(0, (t + 2) << 6);
        COMPUTE(1);
        __syncthreads();
    }

#undef STAGE
#undef COMPUTE

    #pragma unroll
    for (int mt = 0; mt < 4; mt++) {
        #pragma unroll
        for (int reg = 0; reg < 4; reg++) {
            int grow = m0 + wm + mt * 16 + (quad << 2) + reg;
            if (grow >= MROWS) continue;
            #pragma unroll
            for (int nt = 0; nt < 4; nt++) {
                int gcol = nn + wn + nt * 16 + ln;
                Cf[(size_t)grow * DIMC + gcol] = acc[mt][nt][reg] + pb[gcol];
            }
        }
    }
}

// ---------------------------------------------------------------------------
// Flash MFMA attention (R7/R9 single-buffered body, 26.6KB, 6 blocks/CU).
// 64 Q-rows/block, 4 waves; grid 2304, h-major XCD remap. exp2 softmax,
// C-init -SMAX*log2e. (R12 body, unchanged.)
// ---------------------------------------------------------------------------
__global__ __launch_bounds__(256) void attn_mfma(
    const u16* __restrict__ Qg, const u16* __restrict__ Kg,
    const u16* __restrict__ Vg, const u16* __restrict__ bias,
    u16* __restrict__ ctx)
{
    __shared__ __align__(16) u16 KsL[4096];        // [chunk(8)][jr(64)][8]
    __shared__ __align__(16) u16 VtL[64 * 72];     // [d][j^swz], stride 72
    __shared__ __align__(16) u16 Pw[4][16][72];    // [w][m][k^swz]

    const int tid = threadIdx.x;
    const int lane = tid & 63, w = tid >> 6;
    const int quad = lane >> 4, ln = lane & 15;

    // h-major XCD-chunked remap (bijective: 2304 = 8 * 288).
    const int flat = (blockIdx.z * 12 + blockIdx.y) * 12 + blockIdx.x;
    const int wg = (flat & 7) * 288 + (flat >> 3);
    const int h = wg / 192;
    const int rem = wg - h * 192;
    const int b = rem / 12;
    const int q0 = (rem - b * 12) << 6;

    const int mbase = q0 + (w << 4);               // wave's 16 rows
    const u16* bp = bias + ((size_t)h * NTOK) * 768;

    // Q fragments (A-layout), held for the whole kernel
    bf16x8 aq[2];
    {
        int qrow = mbase + ln; if (qrow >= NTOK) qrow = NTOK - 1;
        #pragma unroll
        for (int kp = 0; kp < 2; kp++)
            aq[kp] = *(const bf16x8*)(Qg + ((size_t)(b * NTOK + qrow)) * DIMC
                                      + h * HDIM + kp * 32 + (quad << 3));
    }
    int boff[4];
    #pragma unroll
    for (int reg = 0; reg < 4; reg++) {
        int rr = mbase + (quad << 2) + reg;
        if (rr >= NTOK) rr = NTOK - 1;
        boff[reg] = rr * 768 + (ln << 2);
    }

    // P read swizzle constant (row = ln)
    const int pswz = ((ln >> 2) & 3) << 4;

    float rs[4] = {};
    f32x4 O[4];
    #pragma unroll
    for (int dt = 0; dt < 4; dt++) O[dt] = (f32x4){0.f, 0.f, 0.f, 0.f};

    for (int j0 = 0; j0 < NTOK; j0 += 64) {
        __syncthreads();
        // K tile via async global->LDS, chunk-major
        #pragma unroll
        for (int l = 0; l < 2; l++) {
            int f = tid + (l << 8);                // 0..511
            int chunk = f >> 6, jr = f & 63;
            int krow = j0 + jr; if (krow >= NTOK) krow = NTOK - 1;
            gl_lds16(Kg + ((size_t)(b * NTOK + krow)) * DIMC + h * HDIM + chunk * 8,
                     KsL + f * 8);
        }
        // bias prefetch into registers
        uint2 bvv[4];
        #pragma unroll
        for (int reg = 0; reg < 4; reg++)
            bvv[reg] = *(const uint2*)(bp + boff[reg] + j0);
        // V tile transposed into XOR-swizzled LDS: elem V^T[d][j] at
        // d*72 + (j ^ ((d>>3)&7)*8)
        #pragma unroll
        for (int l = 0; l < 2; l++) {
            int u = tid + (l << 8);
            int jr = u >> 3, d0 = (u & 7) << 3;
            int vrow = j0 + jr; if (vrow >= NTOK) vrow = NTOK - 1;
            uint4 p = *(const uint4*)(Vg + ((size_t)(b * NTOK + vrow)) * DIMC + h * HDIM + d0);
            const u16* pe = (const u16*)&p;
            int jswz = jr ^ d0;                   // key = d0 (multiple of 8, <64)
            #pragma unroll
            for (int i = 0; i < 8; i++) VtL[(d0 + i) * 72 + jswz] = pe[i];
        }
        __syncthreads();

        // V B-frags, b128 via swizzled offset
        bf16x8 bv[4][2];
        #pragma unroll
        for (int dt = 0; dt < 4; dt++) {
            int key8 = ((dt * 2 + (ln >> 3)) & 7) << 3;
            #pragma unroll
            for (int kp = 0; kp < 2; kp++) {
                int koff = (kp * 32 + (quad << 3)) ^ key8;
                bv[dt][kp] = *(const bf16x8*)&VtL[(dt * 16 + ln) * 72 + koff];
            }
        }

        // S = (Q*log2e/8) K^T - SMAX*log2e (via C-init)
        f32x4 s[4];
        #pragma unroll
        for (int nt = 0; nt < 4; nt++) s[nt] = (f32x4){NEGS, NEGS, NEGS, NEGS};
        __builtin_amdgcn_s_setprio(1);
        #pragma unroll
        for (int kp = 0; kp < 2; kp++)
            #pragma unroll
            for (int nt = 0; nt < 4; nt++) {
                bf16x8 bk = *(const bf16x8*)
                    &KsL[(((kp << 2) + quad) * 64 + nt * 16 + ln) * 8];
                s[nt] = __builtin_amdgcn_mfma_f32_16x16x32_bf16(aq[kp], bk, s[nt], 0, 0, 0);
            }
        __builtin_amdgcn_s_setprio(0);

        // p = exp2(s + b): 1 add + 1 native v_exp_f32 per element
        #pragma unroll
        for (int reg = 0; reg < 4; reg++) {
            uint2 bb = bvv[reg];
            float p0 = __builtin_exp2f(s[0][reg] + bflo(bb.x));
            float p1 = __builtin_exp2f(s[1][reg] + bfhi(bb.x));
            float p2 = __builtin_exp2f(s[2][reg] + bflo(bb.y));
            float p3 = __builtin_exp2f(s[3][reg] + bfhi(bb.y));
            s[0][reg] = p0; s[1][reg] = p1;
            s[2][reg] = p2; s[3][reg] = p3;
            rs[reg] += p0 + p1 + p2 + p3;
        }
        // P: C-layout -> A-layout through swizzled wave-private LDS
        u16* pwb = &Pw[w][0][0];
        #pragma unroll
        for (int nt = 0; nt < 4; nt++) {
            int colw = ((nt ^ quad) << 4) + ln;
            #pragma unroll
            for (int reg = 0; reg < 4; reg++)
                pwb[((quad << 2) + reg) * 72 + colw] = f2bf(s[nt][reg]);
        }
        bf16x8 ap[2];
        #pragma unroll
        for (int kp = 0; kp < 2; kp++) {
            int koff = (kp * 32 + (quad << 3)) ^ pswz;
            ap[kp] = *(const bf16x8*)&pwb[ln * 72 + koff];
        }
        // O += P V
        __builtin_amdgcn_s_setprio(1);
        #pragma unroll
        for (int dt = 0; dt < 4; dt++)
            #pragma unroll
            for (int kp = 0; kp < 2; kp++)
                O[dt] = __builtin_amdgcn_mfma_f32_16x16x32_bf16(
                    ap[kp], bv[dt][kp], O[dt], 0, 0, 0);
        __builtin_amdgcn_s_setprio(0);
    }

    // normalize + store
    #pragma unroll
    for (int reg = 0; reg < 4; reg++) {
        float t = rs[reg];
        #pragma unroll
        for (int mk = 8; mk >= 1; mk >>= 1) t += __shfl_xor(t, mk);
        float inv = 1.0f / t;
        int row = mbase + (quad << 2) + reg;
        if (row < NTOK) {
            #pragma unroll
            for (int dt = 0; dt < 4; dt++)
                ctx[((size_t)(b * NTOK + row)) * DIMC + h * HDIM + dt * 16 + ln]
                    = f2bf(O[dt][reg] * inv);
        }
    }
}

// ---------------------------------------------------------------------------
extern "C" void kernel_launch(void* const* d_in, const int* in_sizes, int n_in,
                              void* d_out, int out_size, void* d_ws, size_t ws_size,
                              hipStream_t stream)
{
    const float* x        = (const float*)d_in[0];
    const float* temp_q   = (const float*)d_in[1];
    const float* target_q = (const float*)d_in[2];
    const float* q_w      = (const float*)d_in[3];
    const float* k_w      = (const float*)d_in[4];
    const float* v_w      = (const float*)d_in[5];
    const float* proj_w   = (const float*)d_in[6];
    const float* proj_b   = (const float*)d_in[7];
    const float* rpb      = (const float*)d_in[8];
    const float* rpbt     = (const float*)d_in[9];
    const float* pw1      = (const float*)d_in[10];
    const float* pb1      = (const float*)d_in[11];
    const float* pw2      = (const float*)d_in[12];
    const float* pb2      = (const float*)d_in[13];
    const float* tab      = (const float*)d_in[14];
    const int*   tidx     = (const int*)d_in[15];
    const int*   gidx     = (const int*)d_in[16];
    float* out = (float*)d_out;

    char* ws = (char*)d_ws;
    const size_t S = (size_t)MROWS * DIMC * sizeof(u16);          // 18,186,240
    const size_t SZB = (size_t)NHEAD * NTOK * 768 * sizeof(u16);  // 13,639,680
    u16* XB    = (u16*)(ws);           // CTX aliases XB (XB dead after qkv)
    u16* V     = (u16*)(ws + S);
    u16* Q     = (u16*)(ws + 2 * S);
    u16* K     = (u16*)(ws + 3 * S);
    u16* CTX   = XB;
    u16* BIAS2 = (u16*)(ws + 4 * S);
    u16* WT    = (u16*)(ws + 4 * S + SZB);                        // 4 x 768 x 768

    prep_kernel<<<dim3(PREP_ALL), 256, 0, stream>>>(
        x, XB, q_w, k_w, v_w, proj_w, WT,
        rpb, rpbt, tidx, gidx,
        pw1, pb1, pw2, pb2, tab, BIAS2);

    const u16* WTp = WT + 3 * (size_t)DIMC * DIMC;

    gemm_qkv<<<dim3(18, 185), 256, 0, stream>>>(temp_q, target_q, XB, WT, Q, K, V);
    attn_mfma<<<dim3(12, 12, 16), 256, 0, stream>>>(Q, K, V, BIAS2, CTX);
    gemm_proj<<<dim3(6, 93), 256, 0, stream>>>(CTX, WTp, proj_b, out);
}